// Round 3
// baseline (2423.130 us; speedup 1.0000x reference)
//
#include <hip/hip_runtime.h>
#include <hip/hip_cooperative_groups.h>
#include <cstdint>
#include <cstddef>

namespace cg = cooperative_groups;

#define TT 64
#define BB 32
#define SS 256
#define DH 512
#define VV 32000
#define NROWS 2048   // T*B
#define G4 2048      // 4*DH

typedef __attribute__((ext_vector_type(8))) short short8;
typedef __attribute__((ext_vector_type(4))) float f32x4;

__device__ __forceinline__ unsigned short f2bf(float x) {
    unsigned u = __float_as_uint(x);
    u += 0x7FFFu + ((u >> 16) & 1u);   // RNE
    return (unsigned short)(u >> 16);
}

__device__ __forceinline__ void gload_lds16(const void* g, void* l) {
    __builtin_amdgcn_global_load_lds(
        (const __attribute__((address_space(1))) unsigned int*)g,
        (__attribute__((address_space(3))) unsigned int*)l, 16, 0, 0);
}

// ---------------- prep kernels ----------------
__global__ void k_bsum(const float* __restrict__ bi, const float* __restrict__ bh,
                       float* __restrict__ bs) {
    int i = blockIdx.x * blockDim.x + threadIdx.x;
    if (i < G4) bs[i] = bi[i] + bh[i];
}

__global__ void k_convert_bf16(const float* __restrict__ src,
                               unsigned short* __restrict__ dst, int n4) {
    int i = blockIdx.x * blockDim.x + threadIdx.x;
    int stride = gridDim.x * blockDim.x;
    for (; i < n4; i += stride) {
        float4 v = ((const float4*)src)[i];
        ushort4 o;
        o.x = f2bf(v.x); o.y = f2bf(v.y); o.z = f2bf(v.z); o.w = f2bf(v.w);
        ((ushort4*)dst)[i] = o;
    }
}

__global__ void k_gather_embed32(const int* __restrict__ xseq,
                                 const float* __restrict__ emb,
                                 float* __restrict__ ef) {
    int r = blockIdx.x;                     // 0..2047 (t*32+b)
    int tok = xseq[r];
    const float4* s = (const float4*)(emb + (size_t)tok * DH);
    float4* d = (float4*)(ef + (size_t)r * DH);
    for (int i = threadIdx.x; i < DH / 4; i += blockDim.x) d[i] = s[i];
}

// ---------------- fp32 SGEMM: C[M,N] = A[M,K] @ B[N,K]^T + bias ----------------
__global__ __launch_bounds__(256)
void k_sgemm_xpart(const float* __restrict__ A, const float* __restrict__ B,
                   const float* __restrict__ bias, float* __restrict__ C,
                   int M, int N, int K) {
    __shared__ float As[16][128];
    __shared__ float Bs[16][132];

    const int tid = threadIdx.x;
    const int tx = tid & 15, ty = tid >> 4;
    const int m0 = blockIdx.y * 128, n0 = blockIdx.x * 128;
    const int r = tid >> 1;               // 0..127
    const int c8 = (tid & 1) * 8;         // 0 or 8

    float acc[8][8] = {};

    for (int kt = 0; kt < K; kt += 16) {
        float4 a0 = *(const float4*)&A[(size_t)(m0 + r) * K + kt + c8];
        float4 a1 = *(const float4*)&A[(size_t)(m0 + r) * K + kt + c8 + 4];
        float4 b0 = *(const float4*)&B[(size_t)(n0 + r) * K + kt + c8];
        float4 b1 = *(const float4*)&B[(size_t)(n0 + r) * K + kt + c8 + 4];
        __syncthreads();   // previous iter's LDS reads done
        As[c8 + 0][r] = a0.x; As[c8 + 1][r] = a0.y; As[c8 + 2][r] = a0.z; As[c8 + 3][r] = a0.w;
        As[c8 + 4][r] = a1.x; As[c8 + 5][r] = a1.y; As[c8 + 6][r] = a1.z; As[c8 + 7][r] = a1.w;
        Bs[c8 + 0][r] = b0.x; Bs[c8 + 1][r] = b0.y; Bs[c8 + 2][r] = b0.z; Bs[c8 + 3][r] = b0.w;
        Bs[c8 + 4][r] = b1.x; Bs[c8 + 5][r] = b1.y; Bs[c8 + 6][r] = b1.z; Bs[c8 + 7][r] = b1.w;
        __syncthreads();
#pragma unroll
        for (int kk = 0; kk < 16; ++kk) {
            float4 av0 = *(const float4*)&As[kk][ty * 8];
            float4 av1 = *(const float4*)&As[kk][ty * 8 + 4];
            float4 bv0 = *(const float4*)&Bs[kk][tx * 8];
            float4 bv1 = *(const float4*)&Bs[kk][tx * 8 + 4];
            float av[8] = {av0.x, av0.y, av0.z, av0.w, av1.x, av1.y, av1.z, av1.w};
            float bv[8] = {bv0.x, bv0.y, bv0.z, bv0.w, bv1.x, bv1.y, bv1.z, bv1.w};
#pragma unroll
            for (int i = 0; i < 8; ++i)
#pragma unroll
                for (int j = 0; j < 8; ++j)
                    acc[i][j] += av[i] * bv[j];
        }
    }
#pragma unroll
    for (int i = 0; i < 8; ++i) {
        int grow = m0 + ty * 8 + i;
#pragma unroll
        for (int j = 0; j < 8; ++j) {
            int col = n0 + tx * 8 + j;
            C[(size_t)grow * N + col] = acc[i][j] + bias[col];
        }
    }
}

// ---------------- MFMA GEMM: C[M,N] = A[M,K] @ B[N,K]^T (+epilogue) ----------------
// EPI 1: Cbf = bf16(tanh(acc))           (bf16 out)
// EPI 2: Cf = acc + bias[col] (fp32 out) + per-row-tile softmax partials pm/ps
template <int EPI>
__global__ __launch_bounds__(256)
void k_mfma_gemm(const unsigned short* __restrict__ A,
                 const unsigned short* __restrict__ B,
                 int M, int N, int K,
                 const float* __restrict__ bias,
                 float* __restrict__ Cf,
                 unsigned short* __restrict__ Cbf,
                 float* __restrict__ pm, float* __restrict__ ps) {
    __shared__ unsigned short A_s[128 * 64];
    __shared__ unsigned short B_s[128 * 64];
    __shared__ float part_m[2][128];
    __shared__ float part_s[2][128];

    const int tid = threadIdx.x;
    const int lane = tid & 63;
    const int wid = tid >> 6;
    const int wm = wid >> 1, wn = wid & 1;
    const int mrow0 = blockIdx.y * 128;
    const int ncol0 = blockIdx.x * 128;
    const int lr = lane & 15;            // row/col within 16x16 frag
    const int lk = (lane >> 4) * 8;      // k offset within 32-k chunk
    const int rw = (lane >> 4) * 4;      // C row group

    f32x4 acc[4][4] = {};

    for (int kt = 0; kt < K; kt += 64) {
#pragma unroll
        for (int it = 0; it < 4; ++it) {
            int chunk = it * 256 + tid;          // 16B chunk id 0..1023
            int r = chunk >> 3;
            int c = (chunk & 7) * 8;
            gload_lds16(A + (size_t)(mrow0 + r) * K + kt + c, (void*)(A_s + chunk * 8));
            gload_lds16(B + (size_t)(ncol0 + r) * K + kt + c, (void*)(B_s + chunk * 8));
        }
        __syncthreads();
#pragma unroll
        for (int kk = 0; kk < 2; ++kk) {
            short8 afr[4], bfr[4];
#pragma unroll
            for (int i = 0; i < 4; ++i) {
                afr[i] = *(const short8*)&A_s[(wm * 64 + i * 16 + lr) * 64 + kk * 32 + lk];
                bfr[i] = *(const short8*)&B_s[(wn * 64 + i * 16 + lr) * 64 + kk * 32 + lk];
            }
#pragma unroll
            for (int mi = 0; mi < 4; ++mi)
#pragma unroll
                for (int ni = 0; ni < 4; ++ni)
                    acc[mi][ni] = __builtin_amdgcn_mfma_f32_16x16x32_bf16(
                        afr[mi], bfr[ni], acc[mi][ni], 0, 0, 0);
        }
        __syncthreads();
    }

    if constexpr (EPI == 1) {
#pragma unroll
        for (int ni = 0; ni < 4; ++ni) {
            int col = ncol0 + wn * 64 + ni * 16 + lr;
#pragma unroll
            for (int mi = 0; mi < 4; ++mi)
#pragma unroll
                for (int r = 0; r < 4; ++r) {
                    int grow = mrow0 + wm * 64 + mi * 16 + rw + r;
                    Cbf[(size_t)grow * N + col] = f2bf(tanhf(acc[mi][ni][r]));
                }
        }
    } else {
        float bv[4];
#pragma unroll
        for (int ni = 0; ni < 4; ++ni) bv[ni] = bias[ncol0 + wn * 64 + ni * 16 + lr];
#pragma unroll
        for (int mi = 0; mi < 4; ++mi) {
#pragma unroll
            for (int r = 0; r < 4; ++r) {
                int grow = mrow0 + wm * 64 + mi * 16 + rw + r;
                float v[4];
                float mx = -1e30f;
#pragma unroll
                for (int ni = 0; ni < 4; ++ni) {
                    v[ni] = acc[mi][ni][r] + bv[ni];
                    int col = ncol0 + wn * 64 + ni * 16 + lr;
                    Cf[(size_t)grow * N + col] = v[ni];
                    mx = fmaxf(mx, v[ni]);
                }
#pragma unroll
                for (int d = 1; d <= 8; d <<= 1) mx = fmaxf(mx, __shfl_xor(mx, d));
                float ssum = 0.f;
#pragma unroll
                for (int ni = 0; ni < 4; ++ni) ssum += __expf(v[ni] - mx);
#pragma unroll
                for (int d = 1; d <= 8; d <<= 1) ssum += __shfl_xor(ssum, d);
                if (lr == 0) {
                    int lrow = wm * 64 + mi * 16 + rw + r;
                    part_m[wn][lrow] = mx;
                    part_s[wn][lrow] = ssum;
                }
            }
        }
        __syncthreads();
        if (tid < 128) {
            float m0v = part_m[0][tid], m1v = part_m[1][tid];
            float mm = fmaxf(m0v, m1v);
            float ssum = part_s[0][tid] * __expf(m0v - mm) + part_s[1][tid] * __expf(m1v - mm);
            int grow = mrow0 + tid;
            pm[(size_t)grow * gridDim.x + blockIdx.x] = mm;
            ps[(size_t)grow * gridDim.x + blockIdx.x] = ssum;
        }
    }
}

// ---------------- LSTM scan (cooperative, 64 steps, grid.sync per step) ----------------
// LDS: h transposed [k][b] ([512][32] = 64 KB, bank = b -> conflict-free);
//      W_hh block slice (16 rows x 512 = 32 KB) staged ONCE before the t-loop.
// k-split partner is lane tid^32 (same wave) -> combine via __shfl_xor, no LDS.
__global__ __launch_bounds__(256)
void k_lstm_scan(const float* __restrict__ xpart, const float* __restrict__ Whh,
                 const float* __restrict__ h0, const float* __restrict__ c0,
                 float* __restrict__ hA, float* __restrict__ hB,
                 float* __restrict__ Hall, unsigned short* __restrict__ catbuf,
                 float* __restrict__ hf, float* __restrict__ cf) {
    cg::grid_group grid = cg::this_grid();
    __shared__ float h_lds[DH * 32];     // [k][b]  64 KB
    __shared__ float W_lds[16 * DH];     // [(g*4+jl)][k]  32 KB

    const int tid = threadIdx.x;
    const int b = tid & 31;
    const int sub = tid >> 5;          // 0..7
    const int kh = sub & 1;            // k-half; partner lane = tid^32 (same wave)
    const int jl = sub >> 1;           // 0..3
    const int jj = blockIdx.x * 4 + jl;

    // stage this block's W_hh rows once: rows (g*DH + blockIdx.x*4 + jlr), g=0..3, jlr=0..3
    for (int i = tid; i < 16 * DH / 4; i += 256) {
        int rr = i >> 7;               // 0..15 = g*4 + jlr
        int c4 = i & 127;
        int g = rr >> 2, jlr = rr & 3;
        float4 v = *(const float4*)(Whh + ((size_t)(g * DH + blockIdx.x * 4 + jlr)) * DH + c4 * 4);
        *(float4*)&W_lds[rr * DH + c4 * 4] = v;
    }

    float creg = c0[b * DH + jj];      // used only by kh==0 lanes

    const float* wp0 = &W_lds[(0 * 4 + jl) * DH + kh * 256];
    const float* wp1 = &W_lds[(1 * 4 + jl) * DH + kh * 256];
    const float* wp2 = &W_lds[(2 * 4 + jl) * DH + kh * 256];
    const float* wp3 = &W_lds[(3 * 4 + jl) * DH + kh * 256];

    for (int t = 0; t < TT; ++t) {
        const float* hsrc = (t == 0) ? h0 : ((t & 1) ? hA : hB);
        // stage h (32x512) transposed: h_lds[k*32 + b]
        for (int i = tid; i < 32 * DH / 4; i += 256) {
            int b2 = i & 31, k4 = i >> 5;       // k4 0..127
            float4 v = *(const float4*)(hsrc + (size_t)b2 * DH + k4 * 4);
            h_lds[(k4 * 4 + 0) * 32 + b2] = v.x;
            h_lds[(k4 * 4 + 1) * 32 + b2] = v.y;
            h_lds[(k4 * 4 + 2) * 32 + b2] = v.z;
            h_lds[(k4 * 4 + 3) * 32 + b2] = v.w;
        }
        __syncthreads();

        float a0 = 0.f, a1 = 0.f, a2 = 0.f, a3 = 0.f;
        const float* hp = &h_lds[kh * 256 * 32 + b];
#pragma unroll 4
        for (int k4 = 0; k4 < 64; ++k4) {
            float4 v0 = *(const float4*)&wp0[k4 * 4];
            float4 v1 = *(const float4*)&wp1[k4 * 4];
            float4 v2 = *(const float4*)&wp2[k4 * 4];
            float4 v3 = *(const float4*)&wp3[k4 * 4];
            float hx = hp[(k4 * 4 + 0) * 32], hy = hp[(k4 * 4 + 1) * 32];
            float hz = hp[(k4 * 4 + 2) * 32], hw = hp[(k4 * 4 + 3) * 32];
            a0 += hx * v0.x + hy * v0.y + hz * v0.z + hw * v0.w;
            a1 += hx * v1.x + hy * v1.y + hz * v1.z + hw * v1.w;
            a2 += hx * v2.x + hy * v2.y + hz * v2.z + hw * v2.w;
            a3 += hx * v3.x + hy * v3.y + hz * v3.z + hw * v3.w;
        }
        // combine k-halves: partner lane differs only in bit 5 (kh)
        a0 += __shfl_xor(a0, 32);
        a1 += __shfl_xor(a1, 32);
        a2 += __shfl_xor(a2, 32);
        a3 += __shfl_xor(a3, 32);

        if (kh == 0) {
            const float* xp = xpart + (size_t)(t * BB + b) * G4;
            float gi = a0 + xp[0 * DH + jj];
            float gf = a1 + xp[1 * DH + jj];
            float gg = a2 + xp[2 * DH + jj];
            float go = a3 + xp[3 * DH + jj];
            float si = 1.f / (1.f + __expf(-gi));
            float sf = 1.f / (1.f + __expf(-gf));
            float tg = tanhf(gg);
            float so = 1.f / (1.f + __expf(-go));
            creg = sf * creg + si * tg;
            float hn = so * tanhf(creg);
            float* wb = (t & 1) ? hB : hA;
            wb[b * DH + jj] = hn;
            int row = t * BB + b;
            Hall[(size_t)row * DH + jj] = hn;
            catbuf[(size_t)row * 1024 + jj] = f2bf(hn);
            if (t == TT - 1) {
                hf[b * DH + jj] = hn;
                cf[b * DH + jj] = creg;
            }
        }
        grid.sync();
    }
}

// ---------------- attention: scores -> softmax -> wctx (per (b, 4 t's)) ----------------
__global__ __launch_bounds__(256)
void k_attn(const float* __restrict__ Hall, const float* __restrict__ ctx,
            unsigned short* __restrict__ catbuf) {
    __shared__ float h4[4][DH];
    __shared__ float p_lds[4][SS];
    __shared__ float l_lds[4];

    const int tid = threadIdx.x;
    const int b = blockIdx.x & 31;     // b minor: stable XCD->b mapping for ctx L2 reuse
    const int tg = blockIdx.x >> 5;

    for (int i = tid; i < 4 * DH / 4; i += 256) {
        int e = i * 4;
        int ti = e >> 9, k = e & 511;
        float4 v = *(const float4*)(Hall + ((size_t)((tg * 4 + ti) * BB + b)) * DH + k);
        h4[ti][k + 0] = v.x; h4[ti][k + 1] = v.y; h4[ti][k + 2] = v.z; h4[ti][k + 3] = v.w;
    }
    __syncthreads();

    {   // scores: thread = s
        int s = tid;
        float acc[4] = {0.f, 0.f, 0.f, 0.f};
        const float4* cp = (const float4*)(ctx + ((size_t)b * SS + s) * DH);
        for (int kc = 0; kc < DH / 4; ++kc) {
            float4 cv = cp[kc];
#pragma unroll
            for (int i = 0; i < 4; ++i) {
                float4 hv = *(const float4*)&h4[i][kc * 4];
                acc[i] += cv.x * hv.x + cv.y * hv.y + cv.z * hv.z + cv.w * hv.w;
            }
        }
#pragma unroll
        for (int i = 0; i < 4; ++i) p_lds[i][s] = acc[i];
    }
    __syncthreads();

    {   // softmax per t-row; wave w owns row w
        int w = tid >> 6, l = tid & 63;
        float v0 = p_lds[w][l], v1 = p_lds[w][l + 64];
        float v2 = p_lds[w][l + 128], v3 = p_lds[w][l + 192];
        float mx = fmaxf(fmaxf(v0, v1), fmaxf(v2, v3));
        for (int d = 1; d < 64; d <<= 1) mx = fmaxf(mx, __shfl_xor(mx, d));
        float e0 = __expf(v0 - mx), e1 = __expf(v1 - mx);
        float e2 = __expf(v2 - mx), e3 = __expf(v3 - mx);
        float ssum = e0 + e1 + e2 + e3;
        for (int d = 1; d < 64; d <<= 1) ssum += __shfl_xor(ssum, d);
        p_lds[w][l] = e0; p_lds[w][l + 64] = e1;
        p_lds[w][l + 128] = e2; p_lds[w][l + 192] = e3;
        if (l == 0) l_lds[w] = ssum;
    }
    __syncthreads();

    {   // wctx: thread owns d0 = 2*tid, accumulate over s
        int d0 = tid * 2;
        float accx[4], accy[4];
#pragma unroll
        for (int i = 0; i < 4; ++i) { accx[i] = 0.f; accy[i] = 0.f; }
        const float* cb = ctx + (size_t)b * SS * DH + d0;
        for (int s = 0; s < SS; ++s) {
            float2 cv = *(const float2*)(cb + (size_t)s * DH);
#pragma unroll
            for (int i = 0; i < 4; ++i) {
                float p = p_lds[i][s];
                accx[i] += p * cv.x;
                accy[i] += p * cv.y;
            }
        }
#pragma unroll
        for (int i = 0; i < 4; ++i) {
            float inv = 1.f / l_lds[i];
            int row = (tg * 4 + i) * BB + b;
            unsigned pack = (unsigned)f2bf(accx[i] * inv) | ((unsigned)f2bf(accy[i] * inv) << 16);
            *(unsigned*)&catbuf[(size_t)row * 1024 + DH + d0] = pack;
        }
    }
}

// ---------------- lse combine + subtract ----------------
__global__ void k_lse(const float* __restrict__ pm, const float* __restrict__ ps,
                      float* __restrict__ lse, int nt) {
    int r = blockIdx.x * blockDim.x + threadIdx.x;
    if (r >= NROWS) return;
    const float* pmr = pm + (size_t)r * nt;
    const float* psr = ps + (size_t)r * nt;
    float m = -1e30f;
    for (int i = 0; i < nt; ++i) m = fmaxf(m, pmr[i]);
    float s = 0.f;
    for (int i = 0; i < nt; ++i) s += psr[i] * __expf(pmr[i] - m);
    lse[r] = m + logf(s);
}

__global__ __launch_bounds__(256)
void k_sub(float* __restrict__ logp, const float* __restrict__ lse) {
    int row = blockIdx.x;
    float L = lse[row];
    float4* p = (float4*)(logp + (size_t)row * VV);
    for (int i = threadIdx.x; i < VV / 4; i += 256) {
        float4 v = p[i];
        v.x -= L; v.y -= L; v.z -= L; v.w -= L;
        p[i] = v;
    }
}

// ---------------- host launch ----------------
extern "C" void kernel_launch(void* const* d_in, const int* in_sizes, int n_in,
                              void* d_out, int out_size, void* d_ws, size_t ws_size,
                              hipStream_t stream) {
    const int*   xseq  = (const int*)d_in[0];
    const float* h0    = (const float*)d_in[1];
    const float* c0    = (const float*)d_in[2];
    const float* ctx   = (const float*)d_in[3];
    const float* emb   = (const float*)d_in[4];
    const float* Wih   = (const float*)d_in[5];
    const float* Whh   = (const float*)d_in[6];
    const float* bih   = (const float*)d_in[7];
    const float* bhh   = (const float*)d_in[8];
    const float* Wattn = (const float*)d_in[9];
    const float* Wout  = (const float*)d_in[10];
    const float* bout  = (const float*)d_in[11];
    float* out = (float*)d_out;

    char* wptr = (char*)d_ws;
    auto carve = [&](size_t bytes) {
        char* p = wptr;
        wptr += (bytes + 255) & ~(size_t)255;
        return p;
    };
    float*          xpart   = (float*)carve((size_t)NROWS * G4 * 4);
    float*          Hall    = (float*)carve((size_t)NROWS * DH * 4);
    unsigned short* catbf   = (unsigned short*)carve((size_t)NROWS * 1024 * 2);
    unsigned short* outsbf  = (unsigned short*)carve((size_t)NROWS * DH * 2);
    float*          ef32    = (float*)carve((size_t)NROWS * DH * 4);
    unsigned short* Wattnbf = (unsigned short*)carve((size_t)DH * 1024 * 2);
    unsigned short* Woutbf  = (unsigned short*)carve((size_t)VV * DH * 2);
    float*          bsum    = (float*)carve((size_t)G4 * 4);
    float*          hA      = (float*)carve((size_t)BB * DH * 4);
    float*          hB      = (float*)carve((size_t)BB * DH * 4);
    float*          pm      = (float*)carve((size_t)NROWS * 250 * 4);
    float*          ps      = (float*)carve((size_t)NROWS * 250 * 4);
    float*          lse     = (float*)carve((size_t)NROWS * 4);

    // prep
    k_bsum<<<8, 256, 0, stream>>>(bih, bhh, bsum);
    k_convert_bf16<<<256, 256, 0, stream>>>(Wattn, Wattnbf, DH * 1024 / 4);
    k_convert_bf16<<<2048, 256, 0, stream>>>(Wout, Woutbf, VV * DH / 4);
    k_gather_embed32<<<NROWS, 128, 0, stream>>>(xseq, emb, ef32);

    // x_part = e @ W_ih^T + (b_ih + b_hh)   -- full fp32
    k_sgemm_xpart<<<dim3(16, 16), 256, 0, stream>>>(
        ef32, Wih, bsum, xpart, NROWS, G4, DH);

    // sequential LSTM scan (cooperative)
    {
        const float* a0 = xpart; const float* a1 = Whh;
        const float* a2 = h0;    const float* a3 = c0;
        float* a4 = hA; float* a5 = hB; float* a6 = Hall;
        unsigned short* a7 = catbf;
        float* a8 = out + (size_t)NROWS * VV;           // hf
        float* a9 = a8 + BB * DH;                       // cf
        void* args[] = {&a0, &a1, &a2, &a3, &a4, &a5, &a6, &a7, &a8, &a9};
        hipLaunchCooperativeKernel((const void*)k_lstm_scan, dim3(128), dim3(256),
                                   args, 0, stream);
    }

    // attention (parallel over all t,b)
    k_attn<<<512, 256, 0, stream>>>(Hall, ctx, catbf);

    // outs = tanh(cat @ W_attn^T)  -> bf16
    k_mfma_gemm<1><<<dim3(4, 16), 256, 0, stream>>>(
        catbf, Wattnbf, NROWS, DH, 1024, nullptr, nullptr, outsbf, nullptr, nullptr);

    // logits = outs @ W_out^T + b_out -> d_out (fp32) + softmax partials
    k_mfma_gemm<2><<<dim3(250, 16), 256, 0, stream>>>(
        outsbf, Woutbf, NROWS, VV, DH, bout, out, nullptr, pm, ps);

    // lse + in-place logp
    k_lse<<<8, 256, 0, stream>>>(pm, ps, lse, 250);
    k_sub<<<NROWS, 256, 0, stream>>>(out, lse);
}

// Round 4
// 2251.840 us; speedup vs baseline: 1.0761x; 1.0761x over previous
//
#include <hip/hip_runtime.h>
#include <hip/hip_cooperative_groups.h>
#include <cstdint>
#include <cstddef>

namespace cg = cooperative_groups;

#define TT 64
#define BB 32
#define SS 256
#define DH 512
#define VV 32000
#define NROWS 2048   // T*B
#define G4 2048      // 4*DH
#define NBLK_SCAN 128

typedef __attribute__((ext_vector_type(8))) short short8;
typedef __attribute__((ext_vector_type(4))) float f32x4;

__device__ __forceinline__ unsigned short f2bf(float x) {
    unsigned u = __float_as_uint(x);
    u += 0x7FFFu + ((u >> 16) & 1u);   // RNE
    return (unsigned short)(u >> 16);
}

__device__ __forceinline__ void gload_lds16(const void* g, void* l) {
    __builtin_amdgcn_global_load_lds(
        (const __attribute__((address_space(1))) unsigned int*)g,
        (__attribute__((address_space(3))) unsigned int*)l, 16, 0, 0);
}

// coherent (agent-scope, L1/L2-bypassing) element ops for cross-XCD h exchange
__device__ __forceinline__ void coh_store(float* p, float v) {
    __hip_atomic_store(p, v, __ATOMIC_RELAXED, __HIP_MEMORY_SCOPE_AGENT);
}
__device__ __forceinline__ float coh_load(const float* p) {
    return __hip_atomic_load(p, __ATOMIC_RELAXED, __HIP_MEMORY_SCOPE_AGENT);
}

// ---------------- prep kernels ----------------
__global__ void k_bsum(const float* __restrict__ bi, const float* __restrict__ bh,
                       float* __restrict__ bs) {
    int i = blockIdx.x * blockDim.x + threadIdx.x;
    if (i < G4) bs[i] = bi[i] + bh[i];
}

__global__ void k_convert_bf16(const float* __restrict__ src,
                               unsigned short* __restrict__ dst, int n4) {
    int i = blockIdx.x * blockDim.x + threadIdx.x;
    int stride = gridDim.x * blockDim.x;
    for (; i < n4; i += stride) {
        float4 v = ((const float4*)src)[i];
        ushort4 o;
        o.x = f2bf(v.x); o.y = f2bf(v.y); o.z = f2bf(v.z); o.w = f2bf(v.w);
        ((ushort4*)dst)[i] = o;
    }
}

__global__ void k_gather_embed32(const int* __restrict__ xseq,
                                 const float* __restrict__ emb,
                                 float* __restrict__ ef) {
    int r = blockIdx.x;                     // 0..2047 (t*32+b)
    int tok = xseq[r];
    const float4* s = (const float4*)(emb + (size_t)tok * DH);
    float4* d = (float4*)(ef + (size_t)r * DH);
    for (int i = threadIdx.x; i < DH / 4; i += blockDim.x) d[i] = s[i];
}

// zero barrier counters + transpose h0 -> hT0[k][b]  (runs before every scan)
__global__ void k_scan_init(const float* __restrict__ h0, float* __restrict__ hT0,
                            int* __restrict__ cnt) {
    int i = blockIdx.x * blockDim.x + threadIdx.x;
    if (i < TT * 16) cnt[i] = 0;
    if (i < BB * DH) {
        int b = i >> 9, k = i & 511;
        hT0[k * 32 + b] = h0[i];
    }
}

// ---------------- fp32 SGEMM: C[M,N] = A[M,K] @ B[N,K]^T + bias ----------------
__global__ __launch_bounds__(256)
void k_sgemm_xpart(const float* __restrict__ A, const float* __restrict__ B,
                   const float* __restrict__ bias, float* __restrict__ C,
                   int M, int N, int K) {
    __shared__ float As[16][128];
    __shared__ float Bs[16][132];

    const int tid = threadIdx.x;
    const int tx = tid & 15, ty = tid >> 4;
    const int m0 = blockIdx.y * 128, n0 = blockIdx.x * 128;
    const int r = tid >> 1;               // 0..127
    const int c8 = (tid & 1) * 8;         // 0 or 8

    float acc[8][8] = {};

    for (int kt = 0; kt < K; kt += 16) {
        float4 a0 = *(const float4*)&A[(size_t)(m0 + r) * K + kt + c8];
        float4 a1 = *(const float4*)&A[(size_t)(m0 + r) * K + kt + c8 + 4];
        float4 b0 = *(const float4*)&B[(size_t)(n0 + r) * K + kt + c8];
        float4 b1 = *(const float4*)&B[(size_t)(n0 + r) * K + kt + c8 + 4];
        __syncthreads();   // previous iter's LDS reads done
        As[c8 + 0][r] = a0.x; As[c8 + 1][r] = a0.y; As[c8 + 2][r] = a0.z; As[c8 + 3][r] = a0.w;
        As[c8 + 4][r] = a1.x; As[c8 + 5][r] = a1.y; As[c8 + 6][r] = a1.z; As[c8 + 7][r] = a1.w;
        Bs[c8 + 0][r] = b0.x; Bs[c8 + 1][r] = b0.y; Bs[c8 + 2][r] = b0.z; Bs[c8 + 3][r] = b0.w;
        Bs[c8 + 4][r] = b1.x; Bs[c8 + 5][r] = b1.y; Bs[c8 + 6][r] = b1.z; Bs[c8 + 7][r] = b1.w;
        __syncthreads();
#pragma unroll
        for (int kk = 0; kk < 16; ++kk) {
            float4 av0 = *(const float4*)&As[kk][ty * 8];
            float4 av1 = *(const float4*)&As[kk][ty * 8 + 4];
            float4 bv0 = *(const float4*)&Bs[kk][tx * 8];
            float4 bv1 = *(const float4*)&Bs[kk][tx * 8 + 4];
            float av[8] = {av0.x, av0.y, av0.z, av0.w, av1.x, av1.y, av1.z, av1.w};
            float bv[8] = {bv0.x, bv0.y, bv0.z, bv0.w, bv1.x, bv1.y, bv1.z, bv1.w};
#pragma unroll
            for (int i = 0; i < 8; ++i)
#pragma unroll
                for (int j = 0; j < 8; ++j)
                    acc[i][j] += av[i] * bv[j];
        }
    }
#pragma unroll
    for (int i = 0; i < 8; ++i) {
        int grow = m0 + ty * 8 + i;
#pragma unroll
        for (int j = 0; j < 8; ++j) {
            int col = n0 + tx * 8 + j;
            C[(size_t)grow * N + col] = acc[i][j] + bias[col];
        }
    }
}

// ---------------- MFMA GEMM: C[M,N] = A[M,K] @ B[N,K]^T (+epilogue) ----------------
// EPI 1: Cbf = bf16(tanh(acc))           (bf16 out)
// EPI 2: Cf = acc + bias[col] (fp32 out) + per-row-tile softmax partials pm/ps
template <int EPI>
__global__ __launch_bounds__(256)
void k_mfma_gemm(const unsigned short* __restrict__ A,
                 const unsigned short* __restrict__ B,
                 int M, int N, int K,
                 const float* __restrict__ bias,
                 float* __restrict__ Cf,
                 unsigned short* __restrict__ Cbf,
                 float* __restrict__ pm, float* __restrict__ ps) {
    __shared__ unsigned short A_s[128 * 64];
    __shared__ unsigned short B_s[128 * 64];
    __shared__ float part_m[2][128];
    __shared__ float part_s[2][128];

    const int tid = threadIdx.x;
    const int lane = tid & 63;
    const int wid = tid >> 6;
    const int wm = wid >> 1, wn = wid & 1;
    const int mrow0 = blockIdx.y * 128;
    const int ncol0 = blockIdx.x * 128;
    const int lr = lane & 15;            // row/col within 16x16 frag
    const int lk = (lane >> 4) * 8;      // k offset within 32-k chunk
    const int rw = (lane >> 4) * 4;      // C row group

    f32x4 acc[4][4] = {};

    for (int kt = 0; kt < K; kt += 64) {
#pragma unroll
        for (int it = 0; it < 4; ++it) {
            int chunk = it * 256 + tid;          // 16B chunk id 0..1023
            int r = chunk >> 3;
            int c = (chunk & 7) * 8;
            gload_lds16(A + (size_t)(mrow0 + r) * K + kt + c, (void*)(A_s + chunk * 8));
            gload_lds16(B + (size_t)(ncol0 + r) * K + kt + c, (void*)(B_s + chunk * 8));
        }
        __syncthreads();
#pragma unroll
        for (int kk = 0; kk < 2; ++kk) {
            short8 afr[4], bfr[4];
#pragma unroll
            for (int i = 0; i < 4; ++i) {
                afr[i] = *(const short8*)&A_s[(wm * 64 + i * 16 + lr) * 64 + kk * 32 + lk];
                bfr[i] = *(const short8*)&B_s[(wn * 64 + i * 16 + lr) * 64 + kk * 32 + lk];
            }
#pragma unroll
            for (int mi = 0; mi < 4; ++mi)
#pragma unroll
                for (int ni = 0; ni < 4; ++ni)
                    acc[mi][ni] = __builtin_amdgcn_mfma_f32_16x16x32_bf16(
                        afr[mi], bfr[ni], acc[mi][ni], 0, 0, 0);
        }
        __syncthreads();
    }

    if constexpr (EPI == 1) {
#pragma unroll
        for (int ni = 0; ni < 4; ++ni) {
            int col = ncol0 + wn * 64 + ni * 16 + lr;
#pragma unroll
            for (int mi = 0; mi < 4; ++mi)
#pragma unroll
                for (int r = 0; r < 4; ++r) {
                    int grow = mrow0 + wm * 64 + mi * 16 + rw + r;
                    Cbf[(size_t)grow * N + col] = f2bf(tanhf(acc[mi][ni][r]));
                }
        }
    } else {
        float bv[4];
#pragma unroll
        for (int ni = 0; ni < 4; ++ni) bv[ni] = bias[ncol0 + wn * 64 + ni * 16 + lr];
#pragma unroll
        for (int mi = 0; mi < 4; ++mi) {
#pragma unroll
            for (int r = 0; r < 4; ++r) {
                int grow = mrow0 + wm * 64 + mi * 16 + rw + r;
                float v[4];
                float mx = -1e30f;
#pragma unroll
                for (int ni = 0; ni < 4; ++ni) {
                    v[ni] = acc[mi][ni][r] + bv[ni];
                    int col = ncol0 + wn * 64 + ni * 16 + lr;
                    Cf[(size_t)grow * N + col] = v[ni];
                    mx = fmaxf(mx, v[ni]);
                }
#pragma unroll
                for (int d = 1; d <= 8; d <<= 1) mx = fmaxf(mx, __shfl_xor(mx, d));
                float ssum = 0.f;
#pragma unroll
                for (int ni = 0; ni < 4; ++ni) ssum += __expf(v[ni] - mx);
#pragma unroll
                for (int d = 1; d <= 8; d <<= 1) ssum += __shfl_xor(ssum, d);
                if (lr == 0) {
                    int lrow = wm * 64 + mi * 16 + rw + r;
                    part_m[wn][lrow] = mx;
                    part_s[wn][lrow] = ssum;
                }
            }
        }
        __syncthreads();
        if (tid < 128) {
            float m0v = part_m[0][tid], m1v = part_m[1][tid];
            float mm = fmaxf(m0v, m1v);
            float ssum = part_s[0][tid] * __expf(m0v - mm) + part_s[1][tid] * __expf(m1v - mm);
            int grow = mrow0 + tid;
            pm[(size_t)grow * gridDim.x + blockIdx.x] = mm;
            ps[(size_t)grow * gridDim.x + blockIdx.x] = ssum;
        }
    }
}

// ---------------- LSTM scan (cooperative, custom lightweight barrier) ----------------
// h exchanged via hT[k][b] buffers with agent-scope relaxed atomics (sc0/sc1 ops,
// never dirty L2) + arrival counter -- avoids cg::grid.sync()'s per-step
// buffer_wbl2/buffer_inv full-L2 maintenance (was ~26 us/step).
__global__ __launch_bounds__(256)
void k_lstm_scan(const float* __restrict__ xpart, const float* __restrict__ Whh,
                 const float* __restrict__ hT0, const float* __restrict__ c0,
                 float* __restrict__ hTA, float* __restrict__ hTB,
                 float* __restrict__ Hall, unsigned short* __restrict__ catbuf,
                 float* __restrict__ hf, float* __restrict__ cf,
                 int* __restrict__ cnt) {
    __shared__ float h_lds[DH * 32];     // [k][b]  64 KB
    __shared__ float W_lds[16 * DH];     // [(g*4+jl)][k]  32 KB

    const int tid = threadIdx.x;
    const int b = tid & 31;
    const int sub = tid >> 5;          // 0..7
    const int kh = sub & 1;            // k-half; partner lane = tid^32 (same wave)
    const int jl = sub >> 1;           // 0..3
    const int jj = blockIdx.x * 4 + jl;
    const int nblk = gridDim.x;

    // stage this block's W_hh rows once: rows (g*DH + blockIdx.x*4 + jlr), g=0..3, jlr=0..3
    for (int i = tid; i < 16 * DH / 4; i += 256) {
        int rr = i >> 7;               // 0..15 = g*4 + jlr
        int c4 = i & 127;
        int g = rr >> 2, jlr = rr & 3;
        float4 v = *(const float4*)(Whh + ((size_t)(g * DH + blockIdx.x * 4 + jlr)) * DH + c4 * 4);
        *(float4*)&W_lds[rr * DH + c4 * 4] = v;
    }

    float creg = c0[b * DH + jj];      // used only by kh==0 lanes

    const float* wp0 = &W_lds[(0 * 4 + jl) * DH + kh * 256];
    const float* wp1 = &W_lds[(1 * 4 + jl) * DH + kh * 256];
    const float* wp2 = &W_lds[(2 * 4 + jl) * DH + kh * 256];
    const float* wp3 = &W_lds[(3 * 4 + jl) * DH + kh * 256];

    for (int t = 0; t < TT; ++t) {
        const float* hTsrc = (t == 0) ? hT0 : ((t & 1) ? hTA : hTB);
        // stage h (hT layout [k][b]) into LDS via coherent loads (bypass stale L1/L2)
        for (int i = tid; i < DH * 32; i += 256)
            h_lds[i] = coh_load(hTsrc + i);
        __syncthreads();

        float a0 = 0.f, a1 = 0.f, a2 = 0.f, a3 = 0.f;
        const float* hp = &h_lds[kh * 256 * 32 + b];
#pragma unroll 4
        for (int k4 = 0; k4 < 64; ++k4) {
            float4 v0 = *(const float4*)&wp0[k4 * 4];
            float4 v1 = *(const float4*)&wp1[k4 * 4];
            float4 v2 = *(const float4*)&wp2[k4 * 4];
            float4 v3 = *(const float4*)&wp3[k4 * 4];
            float hx = hp[(k4 * 4 + 0) * 32], hy = hp[(k4 * 4 + 1) * 32];
            float hz = hp[(k4 * 4 + 2) * 32], hw = hp[(k4 * 4 + 3) * 32];
            a0 += hx * v0.x + hy * v0.y + hz * v0.z + hw * v0.w;
            a1 += hx * v1.x + hy * v1.y + hz * v1.z + hw * v1.w;
            a2 += hx * v2.x + hy * v2.y + hz * v2.z + hw * v2.w;
            a3 += hx * v3.x + hy * v3.y + hz * v3.z + hw * v3.w;
        }
        // combine k-halves: partner lane differs only in bit 5 (kh)
        a0 += __shfl_xor(a0, 32);
        a1 += __shfl_xor(a1, 32);
        a2 += __shfl_xor(a2, 32);
        a3 += __shfl_xor(a3, 32);

        if (kh == 0) {
            const float* xp = xpart + (size_t)(t * BB + b) * G4;
            float gi = a0 + xp[0 * DH + jj];
            float gf = a1 + xp[1 * DH + jj];
            float gg = a2 + xp[2 * DH + jj];
            float go = a3 + xp[3 * DH + jj];
            float si = 1.f / (1.f + __expf(-gi));
            float sf = 1.f / (1.f + __expf(-gf));
            float tg = tanhf(gg);
            float so = 1.f / (1.f + __expf(-go));
            creg = sf * creg + si * tg;
            float hn = so * tanhf(creg);
            float* wb = (t & 1) ? hTB : hTA;
            coh_store(&wb[jj * 32 + b], hn);          // coherent write-through
            int row = t * BB + b;
            Hall[(size_t)row * DH + jj] = hn;          // normal cached stores
            catbuf[(size_t)row * 1024 + jj] = f2bf(hn);
            if (t == TT - 1) {
                hf[b * DH + jj] = hn;
                cf[b * DH + jj] = creg;
            }
        }

        // ---- lightweight device barrier (no L2 writeback/invalidate) ----
        __syncthreads();   // compiler drains vmcnt before s_barrier -> all stores done
        if (tid == 0) {
            asm volatile("s_waitcnt vmcnt(0)" ::: "memory");
            __hip_atomic_fetch_add(&cnt[t * 16], 1, __ATOMIC_RELAXED,
                                   __HIP_MEMORY_SCOPE_AGENT);
            while (__hip_atomic_load(&cnt[t * 16], __ATOMIC_RELAXED,
                                     __HIP_MEMORY_SCOPE_AGENT) < nblk) {
                __builtin_amdgcn_s_sleep(1);
            }
        }
        __syncthreads();
    }
}

// ---------------- attention: scores -> softmax -> wctx (per (b, 4 t's)) ----------------
__global__ __launch_bounds__(256)
void k_attn(const float* __restrict__ Hall, const float* __restrict__ ctx,
            unsigned short* __restrict__ catbuf) {
    __shared__ float h4[4][DH];
    __shared__ float p_lds[4][SS];
    __shared__ float l_lds[4];

    const int tid = threadIdx.x;
    const int b = blockIdx.x & 31;     // b minor: stable XCD->b mapping for ctx L2 reuse
    const int tg = blockIdx.x >> 5;

    for (int i = tid; i < 4 * DH / 4; i += 256) {
        int e = i * 4;
        int ti = e >> 9, k = e & 511;
        float4 v = *(const float4*)(Hall + ((size_t)((tg * 4 + ti) * BB + b)) * DH + k);
        h4[ti][k + 0] = v.x; h4[ti][k + 1] = v.y; h4[ti][k + 2] = v.z; h4[ti][k + 3] = v.w;
    }
    __syncthreads();

    {   // scores: thread = s
        int s = tid;
        float acc[4] = {0.f, 0.f, 0.f, 0.f};
        const float4* cp = (const float4*)(ctx + ((size_t)b * SS + s) * DH);
        for (int kc = 0; kc < DH / 4; ++kc) {
            float4 cv = cp[kc];
#pragma unroll
            for (int i = 0; i < 4; ++i) {
                float4 hv = *(const float4*)&h4[i][kc * 4];
                acc[i] += cv.x * hv.x + cv.y * hv.y + cv.z * hv.z + cv.w * hv.w;
            }
        }
#pragma unroll
        for (int i = 0; i < 4; ++i) p_lds[i][s] = acc[i];
    }
    __syncthreads();

    {   // softmax per t-row; wave w owns row w
        int w = tid >> 6, l = tid & 63;
        float v0 = p_lds[w][l], v1 = p_lds[w][l + 64];
        float v2 = p_lds[w][l + 128], v3 = p_lds[w][l + 192];
        float mx = fmaxf(fmaxf(v0, v1), fmaxf(v2, v3));
        for (int d = 1; d < 64; d <<= 1) mx = fmaxf(mx, __shfl_xor(mx, d));
        float e0 = __expf(v0 - mx), e1 = __expf(v1 - mx);
        float e2 = __expf(v2 - mx), e3 = __expf(v3 - mx);
        float ssum = e0 + e1 + e2 + e3;
        for (int d = 1; d < 64; d <<= 1) ssum += __shfl_xor(ssum, d);
        p_lds[w][l] = e0; p_lds[w][l + 64] = e1;
        p_lds[w][l + 128] = e2; p_lds[w][l + 192] = e3;
        if (l == 0) l_lds[w] = ssum;
    }
    __syncthreads();

    {   // wctx: thread owns d0 = 2*tid, accumulate over s
        int d0 = tid * 2;
        float accx[4], accy[4];
#pragma unroll
        for (int i = 0; i < 4; ++i) { accx[i] = 0.f; accy[i] = 0.f; }
        const float* cb = ctx + (size_t)b * SS * DH + d0;
        for (int s = 0; s < SS; ++s) {
            float2 cv = *(const float2*)(cb + (size_t)s * DH);
#pragma unroll
            for (int i = 0; i < 4; ++i) {
                float p = p_lds[i][s];
                accx[i] += p * cv.x;
                accy[i] += p * cv.y;
            }
        }
#pragma unroll
        for (int i = 0; i < 4; ++i) {
            float inv = 1.f / l_lds[i];
            int row = (tg * 4 + i) * BB + b;
            unsigned pack = (unsigned)f2bf(accx[i] * inv) | ((unsigned)f2bf(accy[i] * inv) << 16);
            *(unsigned*)&catbuf[(size_t)row * 1024 + DH + d0] = pack;
        }
    }
}

// ---------------- lse combine + subtract ----------------
__global__ void k_lse(const float* __restrict__ pm, const float* __restrict__ ps,
                      float* __restrict__ lse, int nt) {
    int r = blockIdx.x * blockDim.x + threadIdx.x;
    if (r >= NROWS) return;
    const float* pmr = pm + (size_t)r * nt;
    const float* psr = ps + (size_t)r * nt;
    float m = -1e30f;
    for (int i = 0; i < nt; ++i) m = fmaxf(m, pmr[i]);
    float s = 0.f;
    for (int i = 0; i < nt; ++i) s += psr[i] * __expf(pmr[i] - m);
    lse[r] = m + logf(s);
}

__global__ __launch_bounds__(256)
void k_sub(float* __restrict__ logp, const float* __restrict__ lse) {
    int row = blockIdx.x;
    float L = lse[row];
    float4* p = (float4*)(logp + (size_t)row * VV);
    for (int i = threadIdx.x; i < VV / 4; i += 256) {
        float4 v = p[i];
        v.x -= L; v.y -= L; v.z -= L; v.w -= L;
        p[i] = v;
    }
}

// ---------------- host launch ----------------
extern "C" void kernel_launch(void* const* d_in, const int* in_sizes, int n_in,
                              void* d_out, int out_size, void* d_ws, size_t ws_size,
                              hipStream_t stream) {
    const int*   xseq  = (const int*)d_in[0];
    const float* h0    = (const float*)d_in[1];
    const float* c0    = (const float*)d_in[2];
    const float* ctx   = (const float*)d_in[3];
    const float* emb   = (const float*)d_in[4];
    const float* Wih   = (const float*)d_in[5];
    const float* Whh   = (const float*)d_in[6];
    const float* bih   = (const float*)d_in[7];
    const float* bhh   = (const float*)d_in[8];
    const float* Wattn = (const float*)d_in[9];
    const float* Wout  = (const float*)d_in[10];
    const float* bout  = (const float*)d_in[11];
    float* out = (float*)d_out;

    char* wptr = (char*)d_ws;
    auto carve = [&](size_t bytes) {
        char* p = wptr;
        wptr += (bytes + 255) & ~(size_t)255;
        return p;
    };
    float*          xpart   = (float*)carve((size_t)NROWS * G4 * 4);
    float*          Hall    = (float*)carve((size_t)NROWS * DH * 4);
    unsigned short* catbf   = (unsigned short*)carve((size_t)NROWS * 1024 * 2);
    unsigned short* outsbf  = (unsigned short*)carve((size_t)NROWS * DH * 2);
    float*          ef32    = (float*)carve((size_t)NROWS * DH * 4);
    unsigned short* Wattnbf = (unsigned short*)carve((size_t)DH * 1024 * 2);
    unsigned short* Woutbf  = (unsigned short*)carve((size_t)VV * DH * 2);
    float*          bsum    = (float*)carve((size_t)G4 * 4);
    float*          hT0     = (float*)carve((size_t)BB * DH * 4);
    float*          hTA     = (float*)carve((size_t)BB * DH * 4);
    float*          hTB     = (float*)carve((size_t)BB * DH * 4);
    int*            cnt     = (int*)carve((size_t)TT * 16 * 4);
    float*          pm      = (float*)carve((size_t)NROWS * 250 * 4);
    float*          ps      = (float*)carve((size_t)NROWS * 250 * 4);
    float*          lse     = (float*)carve((size_t)NROWS * 4);

    // prep
    k_bsum<<<8, 256, 0, stream>>>(bih, bhh, bsum);
    k_convert_bf16<<<256, 256, 0, stream>>>(Wattn, Wattnbf, DH * 1024 / 4);
    k_convert_bf16<<<2048, 256, 0, stream>>>(Wout, Woutbf, VV * DH / 4);
    k_gather_embed32<<<NROWS, 128, 0, stream>>>(xseq, emb, ef32);
    k_scan_init<<<64, 256, 0, stream>>>(h0, hT0, cnt);

    // x_part = e @ W_ih^T + (b_ih + b_hh)   -- full fp32
    k_sgemm_xpart<<<dim3(16, 16), 256, 0, stream>>>(
        ef32, Wih, bsum, xpart, NROWS, G4, DH);

    // sequential LSTM scan (cooperative for co-residency; custom barrier inside)
    {
        const float* a0 = xpart; const float* a1 = Whh;
        const float* a2 = hT0;   const float* a3 = c0;
        float* a4 = hTA; float* a5 = hTB; float* a6 = Hall;
        unsigned short* a7 = catbf;
        float* a8 = out + (size_t)NROWS * VV;           // hf
        float* a9 = a8 + BB * DH;                       // cf
        int* a10 = cnt;
        void* args[] = {&a0, &a1, &a2, &a3, &a4, &a5, &a6, &a7, &a8, &a9, &a10};
        hipLaunchCooperativeKernel((const void*)k_lstm_scan, dim3(NBLK_SCAN), dim3(256),
                                   args, 0, stream);
    }

    // attention (parallel over all t,b)
    k_attn<<<512, 256, 0, stream>>>(Hall, ctx, catbf);

    // outs = tanh(cat @ W_attn^T)  -> bf16
    k_mfma_gemm<1><<<dim3(4, 16), 256, 0, stream>>>(
        catbf, Wattnbf, NROWS, DH, 1024, nullptr, nullptr, outsbf, nullptr, nullptr);

    // logits = outs @ W_out^T + b_out -> d_out (fp32) + softmax partials
    k_mfma_gemm<2><<<dim3(250, 16), 256, 0, stream>>>(
        outsbf, Woutbf, NROWS, VV, DH, bout, out, nullptr, pm, ps);

    // lse + in-place logp
    k_lse<<<8, 256, 0, stream>>>(pm, ps, lse, 250);
    k_sub<<<NROWS, 256, 0, stream>>>(out, lse);
}

// Round 5
// 1720.579 us; speedup vs baseline: 1.4083x; 1.3088x over previous
//
#include <hip/hip_runtime.h>
#include <hip/hip_cooperative_groups.h>
#include <cstdint>
#include <cstddef>

namespace cg = cooperative_groups;

#define TT 64
#define BB 32
#define SS 256
#define DH 512
#define VV 32000
#define NROWS 2048   // T*B
#define G4 2048      // 4*DH
#define NBLK_SCAN 256

typedef __attribute__((ext_vector_type(8))) short short8;
typedef __attribute__((ext_vector_type(4))) float f32x4;

__device__ __forceinline__ unsigned short f2bf(float x) {
    unsigned u = __float_as_uint(x);
    u += 0x7FFFu + ((u >> 16) & 1u);   // RNE
    return (unsigned short)(u >> 16);
}

__device__ __forceinline__ void gload_lds16(const void* g, void* l) {
    __builtin_amdgcn_global_load_lds(
        (const __attribute__((address_space(1))) unsigned int*)g,
        (__attribute__((address_space(3))) unsigned int*)l, 16, 0, 0);
}

// coherent (agent-scope, L1/L2-bypassing) element ops for cross-XCD h exchange
__device__ __forceinline__ void coh_store(float* p, float v) {
    __hip_atomic_store(p, v, __ATOMIC_RELAXED, __HIP_MEMORY_SCOPE_AGENT);
}

// ---------------- prep kernels ----------------
__global__ void k_bsum(const float* __restrict__ bi, const float* __restrict__ bh,
                       float* __restrict__ bs) {
    int i = blockIdx.x * blockDim.x + threadIdx.x;
    if (i < G4) bs[i] = bi[i] + bh[i];
}

__global__ void k_convert_bf16(const float* __restrict__ src,
                               unsigned short* __restrict__ dst, int n4) {
    int i = blockIdx.x * blockDim.x + threadIdx.x;
    int stride = gridDim.x * blockDim.x;
    for (; i < n4; i += stride) {
        float4 v = ((const float4*)src)[i];
        ushort4 o;
        o.x = f2bf(v.x); o.y = f2bf(v.y); o.z = f2bf(v.z); o.w = f2bf(v.w);
        ((ushort4*)dst)[i] = o;
    }
}

__global__ void k_gather_embed32(const int* __restrict__ xseq,
                                 const float* __restrict__ emb,
                                 float* __restrict__ ef) {
    int r = blockIdx.x;                     // 0..2047 (t*32+b)
    int tok = xseq[r];
    const float4* s = (const float4*)(emb + (size_t)tok * DH);
    float4* d = (float4*)(ef + (size_t)r * DH);
    for (int i = threadIdx.x; i < DH / 4; i += blockDim.x) d[i] = s[i];
}

// zero barrier counters + transpose h0 -> hT0[k][b]
__global__ void k_scan_init(const float* __restrict__ h0, float* __restrict__ hT0,
                            int* __restrict__ cnt) {
    int i = blockIdx.x * blockDim.x + threadIdx.x;
    if (i < TT * 16) cnt[i] = 0;
    if (i < BB * DH) {
        int b = i >> 9, k = i & 511;
        hT0[k * 32 + b] = h0[i];
    }
}

// ---------------- fp32 SGEMM: Ct[N,M] = (A[M,K] @ B[N,K]^T + bias)^T ----------------
// writes TRANSPOSED (col-major rows) for the scan's coalesced per-step loads.
__global__ __launch_bounds__(256)
void k_sgemm_xpart(const float* __restrict__ A, const float* __restrict__ B,
                   const float* __restrict__ bias, float* __restrict__ Ct,
                   int M, int N, int K) {
    __shared__ float As[16][128];
    __shared__ float Bs[16][132];

    const int tid = threadIdx.x;
    const int tx = tid & 15, ty = tid >> 4;
    const int m0 = blockIdx.y * 128, n0 = blockIdx.x * 128;
    const int r = tid >> 1;               // 0..127
    const int c8 = (tid & 1) * 8;         // 0 or 8

    float acc[8][8] = {};

    for (int kt = 0; kt < K; kt += 16) {
        float4 a0 = *(const float4*)&A[(size_t)(m0 + r) * K + kt + c8];
        float4 a1 = *(const float4*)&A[(size_t)(m0 + r) * K + kt + c8 + 4];
        float4 b0 = *(const float4*)&B[(size_t)(n0 + r) * K + kt + c8];
        float4 b1 = *(const float4*)&B[(size_t)(n0 + r) * K + kt + c8 + 4];
        __syncthreads();   // previous iter's LDS reads done
        As[c8 + 0][r] = a0.x; As[c8 + 1][r] = a0.y; As[c8 + 2][r] = a0.z; As[c8 + 3][r] = a0.w;
        As[c8 + 4][r] = a1.x; As[c8 + 5][r] = a1.y; As[c8 + 6][r] = a1.z; As[c8 + 7][r] = a1.w;
        Bs[c8 + 0][r] = b0.x; Bs[c8 + 1][r] = b0.y; Bs[c8 + 2][r] = b0.z; Bs[c8 + 3][r] = b0.w;
        Bs[c8 + 4][r] = b1.x; Bs[c8 + 5][r] = b1.y; Bs[c8 + 6][r] = b1.z; Bs[c8 + 7][r] = b1.w;
        __syncthreads();
#pragma unroll
        for (int kk = 0; kk < 16; ++kk) {
            float4 av0 = *(const float4*)&As[kk][ty * 8];
            float4 av1 = *(const float4*)&As[kk][ty * 8 + 4];
            float4 bv0 = *(const float4*)&Bs[kk][tx * 8];
            float4 bv1 = *(const float4*)&Bs[kk][tx * 8 + 4];
            float av[8] = {av0.x, av0.y, av0.z, av0.w, av1.x, av1.y, av1.z, av1.w};
            float bv[8] = {bv0.x, bv0.y, bv0.z, bv0.w, bv1.x, bv1.y, bv1.z, bv1.w};
#pragma unroll
            for (int i = 0; i < 8; ++i)
#pragma unroll
                for (int j = 0; j < 8; ++j)
                    acc[i][j] += av[i] * bv[j];
        }
    }
#pragma unroll
    for (int i = 0; i < 8; ++i) {
        int grow = m0 + ty * 8 + i;
#pragma unroll
        for (int j = 0; j < 8; ++j) {
            int col = n0 + tx * 8 + j;
            Ct[(size_t)col * M + grow] = acc[i][j] + bias[col];
        }
    }
}

// ---------------- MFMA GEMM: C[M,N] = A[M,K] @ B[N,K]^T (+epilogue) ----------------
template <int EPI>
__global__ __launch_bounds__(256)
void k_mfma_gemm(const unsigned short* __restrict__ A,
                 const unsigned short* __restrict__ B,
                 int M, int N, int K,
                 const float* __restrict__ bias,
                 float* __restrict__ Cf,
                 unsigned short* __restrict__ Cbf,
                 float* __restrict__ pm, float* __restrict__ ps) {
    __shared__ unsigned short A_s[128 * 64];
    __shared__ unsigned short B_s[128 * 64];
    __shared__ float part_m[2][128];
    __shared__ float part_s[2][128];

    const int tid = threadIdx.x;
    const int lane = tid & 63;
    const int wid = tid >> 6;
    const int wm = wid >> 1, wn = wid & 1;
    const int mrow0 = blockIdx.y * 128;
    const int ncol0 = blockIdx.x * 128;
    const int lr = lane & 15;
    const int lk = (lane >> 4) * 8;
    const int rw = (lane >> 4) * 4;

    f32x4 acc[4][4] = {};

    for (int kt = 0; kt < K; kt += 64) {
#pragma unroll
        for (int it = 0; it < 4; ++it) {
            int chunk = it * 256 + tid;
            int r = chunk >> 3;
            int c = (chunk & 7) * 8;
            gload_lds16(A + (size_t)(mrow0 + r) * K + kt + c, (void*)(A_s + chunk * 8));
            gload_lds16(B + (size_t)(ncol0 + r) * K + kt + c, (void*)(B_s + chunk * 8));
        }
        __syncthreads();
#pragma unroll
        for (int kk = 0; kk < 2; ++kk) {
            short8 afr[4], bfr[4];
#pragma unroll
            for (int i = 0; i < 4; ++i) {
                afr[i] = *(const short8*)&A_s[(wm * 64 + i * 16 + lr) * 64 + kk * 32 + lk];
                bfr[i] = *(const short8*)&B_s[(wn * 64 + i * 16 + lr) * 64 + kk * 32 + lk];
            }
#pragma unroll
            for (int mi = 0; mi < 4; ++mi)
#pragma unroll
                for (int ni = 0; ni < 4; ++ni)
                    acc[mi][ni] = __builtin_amdgcn_mfma_f32_16x16x32_bf16(
                        afr[mi], bfr[ni], acc[mi][ni], 0, 0, 0);
        }
        __syncthreads();
    }

    if constexpr (EPI == 1) {
#pragma unroll
        for (int ni = 0; ni < 4; ++ni) {
            int col = ncol0 + wn * 64 + ni * 16 + lr;
#pragma unroll
            for (int mi = 0; mi < 4; ++mi)
#pragma unroll
                for (int r = 0; r < 4; ++r) {
                    int grow = mrow0 + wm * 64 + mi * 16 + rw + r;
                    Cbf[(size_t)grow * N + col] = f2bf(tanhf(acc[mi][ni][r]));
                }
        }
    } else {
        float bv[4];
#pragma unroll
        for (int ni = 0; ni < 4; ++ni) bv[ni] = bias[ncol0 + wn * 64 + ni * 16 + lr];
#pragma unroll
        for (int mi = 0; mi < 4; ++mi) {
#pragma unroll
            for (int r = 0; r < 4; ++r) {
                int grow = mrow0 + wm * 64 + mi * 16 + rw + r;
                float v[4];
                float mx = -1e30f;
#pragma unroll
                for (int ni = 0; ni < 4; ++ni) {
                    v[ni] = acc[mi][ni][r] + bv[ni];
                    int col = ncol0 + wn * 64 + ni * 16 + lr;
                    Cf[(size_t)grow * N + col] = v[ni];
                    mx = fmaxf(mx, v[ni]);
                }
#pragma unroll
                for (int d = 1; d <= 8; d <<= 1) mx = fmaxf(mx, __shfl_xor(mx, d));
                float ssum = 0.f;
#pragma unroll
                for (int ni = 0; ni < 4; ++ni) ssum += __expf(v[ni] - mx);
#pragma unroll
                for (int d = 1; d <= 8; d <<= 1) ssum += __shfl_xor(ssum, d);
                if (lr == 0) {
                    int lrow = wm * 64 + mi * 16 + rw + r;
                    part_m[wn][lrow] = mx;
                    part_s[wn][lrow] = ssum;
                }
            }
        }
        __syncthreads();
        if (tid < 128) {
            float m0v = part_m[0][tid], m1v = part_m[1][tid];
            float mm = fmaxf(m0v, m1v);
            float ssum = part_s[0][tid] * __expf(m0v - mm) + part_s[1][tid] * __expf(m1v - mm);
            int grow = mrow0 + tid;
            pm[(size_t)grow * gridDim.x + blockIdx.x] = mm;
            ps[(size_t)grow * gridDim.x + blockIdx.x] = ssum;
        }
    }
}

// ---------------- LSTM scan: 256 blocks x 128 threads (2 jj/block) ----------------
// h all-gather: batched uncached (sc0 sc1) dwordx4 loads, 16 in flight, 1 waitcnt.
// W slice (8 rows, 16 KB) in LDS; dot is 2-addr-broadcast ds_read_b128.
// Barrier: per-step arrival counter, agent-scope atomics (no L2 flush).
__global__ __launch_bounds__(128)
void k_lstm_scan(const float* __restrict__ xpartT, const float* __restrict__ Whh,
                 const float* __restrict__ hT0, const float* __restrict__ c0,
                 float* __restrict__ hTA, float* __restrict__ hTB,
                 float* __restrict__ Hall, unsigned short* __restrict__ catbuf,
                 float* __restrict__ hf, float* __restrict__ cf,
                 int* __restrict__ cnt) {
    __shared__ float h_lds[DH * 32];     // [k][b]  64 KB
    __shared__ float W_lds[8 * DH];      // [(g*2+jl)][k]  16 KB

    const int tid = threadIdx.x;
    const int b = tid & 31;
    const int kh = (tid >> 5) & 1;       // k-half; partner lane = lane^32 (same wave)
    const int jl = tid >> 6;             // 0..1
    const int jj = blockIdx.x * 2 + jl;
    const int nblk = gridDim.x;

    // stage this block's 8 W_hh rows once
    for (int i = tid; i < 8 * DH / 4; i += 128) {
        int rr = i >> 7;                 // 0..7 = g*2 + jlr
        int c4 = i & 127;
        int g = rr >> 1, jlr = rr & 1;
        float4 v = *(const float4*)(Whh + ((size_t)(g * DH + blockIdx.x * 2 + jlr)) * DH + c4 * 4);
        *(float4*)&W_lds[rr * DH + c4 * 4] = v;
    }

    float creg = c0[b * DH + jj];        // used only by kh==0 lanes

    const float* wp0 = &W_lds[(0 * 2 + jl) * DH + kh * 256];
    const float* wp1 = &W_lds[(1 * 2 + jl) * DH + kh * 256];
    const float* wp2 = &W_lds[(2 * 2 + jl) * DH + kh * 256];
    const float* wp3 = &W_lds[(3 * 2 + jl) * DH + kh * 256];

    for (int t = 0; t < TT; ++t) {
        const float* hTsrc = (t == 0) ? hT0 : ((t & 1) ? hTA : hTB);
        // ---- h all-gather: 128 floats/thread, batched uncached loads ----
        {
            const float* src = hTsrc + tid * 128;
#pragma unroll
            for (int rnd = 0; rnd < 2; ++rnd) {
                f32x4 v[16];
#pragma unroll
                for (int j = 0; j < 16; ++j)
                    asm volatile("global_load_dwordx4 %0, %1, off sc0 sc1"
                                 : "=v"(v[j]) : "v"(src + rnd * 64 + j * 4));
                asm volatile("s_waitcnt vmcnt(0)" ::: "memory");
                __builtin_amdgcn_sched_barrier(0);
#pragma unroll
                for (int j = 0; j < 16; ++j)
                    *(f32x4*)&h_lds[tid * 128 + rnd * 64 + j * 4] = v[j];
            }
        }
        __syncthreads();

        float a0 = 0.f, a1 = 0.f, a2 = 0.f, a3 = 0.f;
        const float* hp = &h_lds[kh * 256 * 32 + b];
#pragma unroll 4
        for (int k4 = 0; k4 < 64; ++k4) {
            float4 v0 = *(const float4*)&wp0[k4 * 4];
            float4 v1 = *(const float4*)&wp1[k4 * 4];
            float4 v2 = *(const float4*)&wp2[k4 * 4];
            float4 v3 = *(const float4*)&wp3[k4 * 4];
            float hx = hp[(k4 * 4 + 0) * 32], hy = hp[(k4 * 4 + 1) * 32];
            float hz = hp[(k4 * 4 + 2) * 32], hw = hp[(k4 * 4 + 3) * 32];
            a0 += hx * v0.x + hy * v0.y + hz * v0.z + hw * v0.w;
            a1 += hx * v1.x + hy * v1.y + hz * v1.z + hw * v1.w;
            a2 += hx * v2.x + hy * v2.y + hz * v2.z + hw * v2.w;
            a3 += hx * v3.x + hy * v3.y + hz * v3.z + hw * v3.w;
        }
        a0 += __shfl_xor(a0, 32);
        a1 += __shfl_xor(a1, 32);
        a2 += __shfl_xor(a2, 32);
        a3 += __shfl_xor(a3, 32);

        if (kh == 0) {
            const float* xt = xpartT + (size_t)t * BB + b;   // + col*NROWS below
            float gi = a0 + xt[(size_t)(0 * DH + jj) * NROWS];
            float gf = a1 + xt[(size_t)(1 * DH + jj) * NROWS];
            float gg = a2 + xt[(size_t)(2 * DH + jj) * NROWS];
            float go = a3 + xt[(size_t)(3 * DH + jj) * NROWS];
            float si = 1.f / (1.f + __expf(-gi));
            float sf = 1.f / (1.f + __expf(-gf));
            float tg = tanhf(gg);
            float so = 1.f / (1.f + __expf(-go));
            creg = sf * creg + si * tg;
            float hn = so * tanhf(creg);
            float* wb = (t & 1) ? hTB : hTA;
            coh_store(&wb[jj * 32 + b], hn);          // write-through to coherence point
            int row = t * BB + b;
            Hall[(size_t)row * DH + jj] = hn;          // normal cached stores
            catbuf[(size_t)row * 1024 + jj] = f2bf(hn);
            if (t == TT - 1) {
                hf[b * DH + jj] = hn;
                cf[b * DH + jj] = creg;
            }
        }

        // ---- lightweight device barrier ----
        __syncthreads();   // drains vmcnt before s_barrier -> h stores done
        if (tid == 0) {
            asm volatile("s_waitcnt vmcnt(0)" ::: "memory");
            __hip_atomic_fetch_add(&cnt[t * 16], 1, __ATOMIC_RELAXED,
                                   __HIP_MEMORY_SCOPE_AGENT);
            while (__hip_atomic_load(&cnt[t * 16], __ATOMIC_RELAXED,
                                     __HIP_MEMORY_SCOPE_AGENT) < nblk) {
                __builtin_amdgcn_s_sleep(1);
            }
        }
        __syncthreads();
    }
}

// ---------------- attention: scores -> softmax -> wctx (per (b, 4 t's)) ----------------
__global__ __launch_bounds__(256)
void k_attn(const float* __restrict__ Hall, const float* __restrict__ ctx,
            unsigned short* __restrict__ catbuf) {
    __shared__ float h4[4][DH];
    __shared__ float p_lds[4][SS];
    __shared__ float l_lds[4];

    const int tid = threadIdx.x;
    const int b = blockIdx.x & 31;
    const int tg = blockIdx.x >> 5;

    for (int i = tid; i < 4 * DH / 4; i += 256) {
        int e = i * 4;
        int ti = e >> 9, k = e & 511;
        float4 v = *(const float4*)(Hall + ((size_t)((tg * 4 + ti) * BB + b)) * DH + k);
        h4[ti][k + 0] = v.x; h4[ti][k + 1] = v.y; h4[ti][k + 2] = v.z; h4[ti][k + 3] = v.w;
    }
    __syncthreads();

    {   // scores: thread = s
        int s = tid;
        float acc[4] = {0.f, 0.f, 0.f, 0.f};
        const float4* cp = (const float4*)(ctx + ((size_t)b * SS + s) * DH);
        for (int kc = 0; kc < DH / 4; ++kc) {
            float4 cv = cp[kc];
#pragma unroll
            for (int i = 0; i < 4; ++i) {
                float4 hv = *(const float4*)&h4[i][kc * 4];
                acc[i] += cv.x * hv.x + cv.y * hv.y + cv.z * hv.z + cv.w * hv.w;
            }
        }
#pragma unroll
        for (int i = 0; i < 4; ++i) p_lds[i][s] = acc[i];
    }
    __syncthreads();

    {   // softmax per t-row; wave w owns row w
        int w = tid >> 6, l = tid & 63;
        float v0 = p_lds[w][l], v1 = p_lds[w][l + 64];
        float v2 = p_lds[w][l + 128], v3 = p_lds[w][l + 192];
        float mx = fmaxf(fmaxf(v0, v1), fmaxf(v2, v3));
        for (int d = 1; d < 64; d <<= 1) mx = fmaxf(mx, __shfl_xor(mx, d));
        float e0 = __expf(v0 - mx), e1 = __expf(v1 - mx);
        float e2 = __expf(v2 - mx), e3 = __expf(v3 - mx);
        float ssum = e0 + e1 + e2 + e3;
        for (int d = 1; d < 64; d <<= 1) ssum += __shfl_xor(ssum, d);
        p_lds[w][l] = e0; p_lds[w][l + 64] = e1;
        p_lds[w][l + 128] = e2; p_lds[w][l + 192] = e3;
        if (l == 0) l_lds[w] = ssum;
    }
    __syncthreads();

    {   // wctx: thread owns d0 = 2*tid
        int d0 = tid * 2;
        float accx[4], accy[4];
#pragma unroll
        for (int i = 0; i < 4; ++i) { accx[i] = 0.f; accy[i] = 0.f; }
        const float* cb = ctx + (size_t)b * SS * DH + d0;
        for (int s = 0; s < SS; ++s) {
            float2 cv = *(const float2*)(cb + (size_t)s * DH);
#pragma unroll
            for (int i = 0; i < 4; ++i) {
                float p = p_lds[i][s];
                accx[i] += p * cv.x;
                accy[i] += p * cv.y;
            }
        }
#pragma unroll
        for (int i = 0; i < 4; ++i) {
            float inv = 1.f / l_lds[i];
            int row = (tg * 4 + i) * BB + b;
            unsigned pack = (unsigned)f2bf(accx[i] * inv) | ((unsigned)f2bf(accy[i] * inv) << 16);
            *(unsigned*)&catbuf[(size_t)row * 1024 + DH + d0] = pack;
        }
    }
}

// ---------------- lse combine + subtract ----------------
__global__ void k_lse(const float* __restrict__ pm, const float* __restrict__ ps,
                      float* __restrict__ lse, int nt) {
    int r = blockIdx.x * blockDim.x + threadIdx.x;
    if (r >= NROWS) return;
    const float* pmr = pm + (size_t)r * nt;
    const float* psr = ps + (size_t)r * nt;
    float m = -1e30f;
    for (int i = 0; i < nt; ++i) m = fmaxf(m, pmr[i]);
    float s = 0.f;
    for (int i = 0; i < nt; ++i) s += psr[i] * __expf(pmr[i] - m);
    lse[r] = m + logf(s);
}

__global__ __launch_bounds__(256)
void k_sub(float* __restrict__ logp, const float* __restrict__ lse) {
    int row = blockIdx.x;
    float L = lse[row];
    float4* p = (float4*)(logp + (size_t)row * VV);
    for (int i = threadIdx.x; i < VV / 4; i += 256) {
        float4 v = p[i];
        v.x -= L; v.y -= L; v.z -= L; v.w -= L;
        p[i] = v;
    }
}

// ---------------- host launch ----------------
extern "C" void kernel_launch(void* const* d_in, const int* in_sizes, int n_in,
                              void* d_out, int out_size, void* d_ws, size_t ws_size,
                              hipStream_t stream) {
    const int*   xseq  = (const int*)d_in[0];
    const float* h0    = (const float*)d_in[1];
    const float* c0    = (const float*)d_in[2];
    const float* ctx   = (const float*)d_in[3];
    const float* emb   = (const float*)d_in[4];
    const float* Wih   = (const float*)d_in[5];
    const float* Whh   = (const float*)d_in[6];
    const float* bih   = (const float*)d_in[7];
    const float* bhh   = (const float*)d_in[8];
    const float* Wattn = (const float*)d_in[9];
    const float* Wout  = (const float*)d_in[10];
    const float* bout  = (const float*)d_in[11];
    float* out = (float*)d_out;

    char* wptr = (char*)d_ws;
    auto carve = [&](size_t bytes) {
        char* p = wptr;
        wptr += (bytes + 255) & ~(size_t)255;
        return p;
    };
    float*          xpartT  = (float*)carve((size_t)NROWS * G4 * 4);
    float*          Hall    = (float*)carve((size_t)NROWS * DH * 4);
    unsigned short* catbf   = (unsigned short*)carve((size_t)NROWS * 1024 * 2);
    unsigned short* outsbf  = (unsigned short*)carve((size_t)NROWS * DH * 2);
    float*          ef32    = (float*)carve((size_t)NROWS * DH * 4);
    unsigned short* Wattnbf = (unsigned short*)carve((size_t)DH * 1024 * 2);
    unsigned short* Woutbf  = (unsigned short*)carve((size_t)VV * DH * 2);
    float*          bsum    = (float*)carve((size_t)G4 * 4);
    float*          hT0     = (float*)carve((size_t)BB * DH * 4);
    float*          hTA     = (float*)carve((size_t)BB * DH * 4);
    float*          hTB     = (float*)carve((size_t)BB * DH * 4);
    int*            cnt     = (int*)carve((size_t)TT * 16 * 4);
    float*          pm      = (float*)carve((size_t)NROWS * 250 * 4);
    float*          ps      = (float*)carve((size_t)NROWS * 250 * 4);
    float*          lse     = (float*)carve((size_t)NROWS * 4);

    // prep
    k_bsum<<<8, 256, 0, stream>>>(bih, bhh, bsum);
    k_convert_bf16<<<256, 256, 0, stream>>>(Wattn, Wattnbf, DH * 1024 / 4);
    k_convert_bf16<<<2048, 256, 0, stream>>>(Wout, Woutbf, VV * DH / 4);
    k_gather_embed32<<<NROWS, 128, 0, stream>>>(xseq, emb, ef32);
    k_scan_init<<<64, 256, 0, stream>>>(h0, hT0, cnt);

    // x_part^T = (e @ W_ih^T + b)^T   -- full fp32, transposed write
    k_sgemm_xpart<<<dim3(16, 16), 256, 0, stream>>>(
        ef32, Wih, bsum, xpartT, NROWS, G4, DH);

    // sequential LSTM scan (cooperative for co-residency; custom barrier inside)
    {
        const float* a0 = xpartT; const float* a1 = Whh;
        const float* a2 = hT0;    const float* a3 = c0;
        float* a4 = hTA; float* a5 = hTB; float* a6 = Hall;
        unsigned short* a7 = catbf;
        float* a8 = out + (size_t)NROWS * VV;           // hf
        float* a9 = a8 + BB * DH;                       // cf
        int* a10 = cnt;
        void* args[] = {&a0, &a1, &a2, &a3, &a4, &a5, &a6, &a7, &a8, &a9, &a10};
        hipLaunchCooperativeKernel((const void*)k_lstm_scan, dim3(NBLK_SCAN), dim3(128),
                                   args, 0, stream);
    }

    // attention (parallel over all t,b)
    k_attn<<<512, 256, 0, stream>>>(Hall, ctx, catbf);

    // outs = tanh(cat @ W_attn^T)  -> bf16
    k_mfma_gemm<1><<<dim3(4, 16), 256, 0, stream>>>(
        catbf, Wattnbf, NROWS, DH, 1024, nullptr, nullptr, outsbf, nullptr, nullptr);

    // logits = outs @ W_out^T + b_out -> d_out (fp32) + softmax partials
    k_mfma_gemm<2><<<dim3(250, 16), 256, 0, stream>>>(
        outsbf, Woutbf, NROWS, VV, DH, bout, out, nullptr, pm, ps);

    // lse + in-place logp
    k_lse<<<8, 256, 0, stream>>>(pm, ps, lse, 250);
    k_sub<<<NROWS, 256, 0, stream>>>(out, lse);
}

// Round 10
// 1495.718 us; speedup vs baseline: 1.6200x; 1.1503x over previous
//
#include <hip/hip_runtime.h>
#include <hip/hip_cooperative_groups.h>
#include <cstdint>
#include <cstddef>

namespace cg = cooperative_groups;

#define TT 64
#define BB 32
#define SS 256
#define DH 512
#define VV 32000
#define NROWS 2048   // T*B
#define G4 2048      // 4*DH
#define NBLK_SCAN 256

typedef __attribute__((ext_vector_type(8))) short short8;
typedef __attribute__((ext_vector_type(4))) float f32x4;

__device__ __forceinline__ unsigned short f2bf(float x) {
    unsigned u = __float_as_uint(x);
    u += 0x7FFFu + ((u >> 16) & 1u);   // RNE
    return (unsigned short)(u >> 16);
}

__device__ __forceinline__ void gload_lds16(const void* g, void* l) {
    __builtin_amdgcn_global_load_lds(
        (const __attribute__((address_space(1))) unsigned int*)g,
        (__attribute__((address_space(3))) unsigned int*)l, 16, 0, 0);
}

// coherent (agent-scope) dword store -- r5-proven cross-XCD exchange primitive
__device__ __forceinline__ void coh_store(float* p, float v) {
    __hip_atomic_store(p, v, __ATOMIC_RELAXED, __HIP_MEMORY_SCOPE_AGENT);
}

// ---------------- prep kernels ----------------
__global__ void k_bsum(const float* __restrict__ bi, const float* __restrict__ bh,
                       float* __restrict__ bs) {
    int i = blockIdx.x * blockDim.x + threadIdx.x;
    if (i < G4) bs[i] = bi[i] + bh[i];
}

__global__ void k_convert_bf16(const float* __restrict__ src,
                               unsigned short* __restrict__ dst, int n4) {
    int i = blockIdx.x * blockDim.x + threadIdx.x;
    int stride = gridDim.x * blockDim.x;
    for (; i < n4; i += stride) {
        float4 v = ((const float4*)src)[i];
        ushort4 o;
        o.x = f2bf(v.x); o.y = f2bf(v.y); o.z = f2bf(v.z); o.w = f2bf(v.w);
        ((ushort4*)dst)[i] = o;
    }
}

__global__ void k_gather_embed32(const int* __restrict__ xseq,
                                 const float* __restrict__ emb,
                                 float* __restrict__ ef) {
    int r = blockIdx.x;
    int tok = xseq[r];
    const float4* s = (const float4*)(emb + (size_t)tok * DH);
    float4* d = (float4*)(ef + (size_t)r * DH);
    for (int i = threadIdx.x; i < DH / 4; i += blockDim.x) d[i] = s[i];
}

// zero barrier counters + transpose h0 -> hT0[k][b]  (verbatim r5)
__global__ void k_scan_init(const float* __restrict__ h0, float* __restrict__ hT0,
                            int* __restrict__ cnt) {
    int i = blockIdx.x * blockDim.x + threadIdx.x;
    if (i < TT * 16) cnt[i] = 0;
    if (i < BB * DH) {
        int b = i >> 9, k = i & 511;
        hT0[k * 32 + b] = h0[i];
    }
}

// ---------------- fp32 SGEMM: Ct[N,M] = (A[M,K] @ B[N,K]^T + bias)^T ----------------
__global__ __launch_bounds__(256)
void k_sgemm_xpart(const float* __restrict__ A, const float* __restrict__ B,
                   const float* __restrict__ bias, float* __restrict__ Ct,
                   int M, int N, int K) {
    __shared__ float As[16][128];
    __shared__ float Bs[16][132];

    const int tid = threadIdx.x;
    const int tx = tid & 15, ty = tid >> 4;
    const int m0 = blockIdx.y * 128, n0 = blockIdx.x * 128;
    const int r = tid >> 1;
    const int c8 = (tid & 1) * 8;

    float acc[8][8] = {};

    for (int kt = 0; kt < K; kt += 16) {
        float4 a0 = *(const float4*)&A[(size_t)(m0 + r) * K + kt + c8];
        float4 a1 = *(const float4*)&A[(size_t)(m0 + r) * K + kt + c8 + 4];
        float4 b0 = *(const float4*)&B[(size_t)(n0 + r) * K + kt + c8];
        float4 b1 = *(const float4*)&B[(size_t)(n0 + r) * K + kt + c8 + 4];
        __syncthreads();
        As[c8 + 0][r] = a0.x; As[c8 + 1][r] = a0.y; As[c8 + 2][r] = a0.z; As[c8 + 3][r] = a0.w;
        As[c8 + 4][r] = a1.x; As[c8 + 5][r] = a1.y; As[c8 + 6][r] = a1.z; As[c8 + 7][r] = a1.w;
        Bs[c8 + 0][r] = b0.x; Bs[c8 + 1][r] = b0.y; Bs[c8 + 2][r] = b0.z; Bs[c8 + 3][r] = b0.w;
        Bs[c8 + 4][r] = b1.x; Bs[c8 + 5][r] = b1.y; Bs[c8 + 6][r] = b1.z; Bs[c8 + 7][r] = b1.w;
        __syncthreads();
#pragma unroll
        for (int kk = 0; kk < 16; ++kk) {
            float4 av0 = *(const float4*)&As[kk][ty * 8];
            float4 av1 = *(const float4*)&As[kk][ty * 8 + 4];
            float4 bv0 = *(const float4*)&Bs[kk][tx * 8];
            float4 bv1 = *(const float4*)&Bs[kk][tx * 8 + 4];
            float av[8] = {av0.x, av0.y, av0.z, av0.w, av1.x, av1.y, av1.z, av1.w};
            float bv[8] = {bv0.x, bv0.y, bv0.z, bv0.w, bv1.x, bv1.y, bv1.z, bv1.w};
#pragma unroll
            for (int i = 0; i < 8; ++i)
#pragma unroll
                for (int j = 0; j < 8; ++j)
                    acc[i][j] += av[i] * bv[j];
        }
    }
#pragma unroll
    for (int i = 0; i < 8; ++i) {
        int grow = m0 + ty * 8 + i;
#pragma unroll
        for (int j = 0; j < 8; ++j) {
            int col = n0 + tx * 8 + j;
            Ct[(size_t)col * M + grow] = acc[i][j] + bias[col];
        }
    }
}

// ---------------- MFMA GEMM: C[M,N] = A[M,K] @ B[N,K]^T (+epilogue) ----------------
template <int EPI>
__global__ __launch_bounds__(256)
void k_mfma_gemm(const unsigned short* __restrict__ A,
                 const unsigned short* __restrict__ B,
                 int M, int N, int K,
                 const float* __restrict__ bias,
                 float* __restrict__ Cf,
                 unsigned short* __restrict__ Cbf,
                 float* __restrict__ pm, float* __restrict__ ps) {
    __shared__ unsigned short A_s[128 * 64];
    __shared__ unsigned short B_s[128 * 64];
    __shared__ float part_m[2][128];
    __shared__ float part_s[2][128];

    const int tid = threadIdx.x;
    const int lane = tid & 63;
    const int wid = tid >> 6;
    const int wm = wid >> 1, wn = wid & 1;
    const int mrow0 = blockIdx.y * 128;
    const int ncol0 = blockIdx.x * 128;
    const int lr = lane & 15;
    const int lk = (lane >> 4) * 8;
    const int rw = (lane >> 4) * 4;

    f32x4 acc[4][4] = {};

    for (int kt = 0; kt < K; kt += 64) {
#pragma unroll
        for (int it = 0; it < 4; ++it) {
            int chunk = it * 256 + tid;
            int r = chunk >> 3;
            int c = (chunk & 7) * 8;
            gload_lds16(A + (size_t)(mrow0 + r) * K + kt + c, (void*)(A_s + chunk * 8));
            gload_lds16(B + (size_t)(ncol0 + r) * K + kt + c, (void*)(B_s + chunk * 8));
        }
        __syncthreads();
#pragma unroll
        for (int kk = 0; kk < 2; ++kk) {
            short8 afr[4], bfr[4];
#pragma unroll
            for (int i = 0; i < 4; ++i) {
                afr[i] = *(const short8*)&A_s[(wm * 64 + i * 16 + lr) * 64 + kk * 32 + lk];
                bfr[i] = *(const short8*)&B_s[(wn * 64 + i * 16 + lr) * 64 + kk * 32 + lk];
            }
#pragma unroll
            for (int mi = 0; mi < 4; ++mi)
#pragma unroll
                for (int ni = 0; ni < 4; ++ni)
                    acc[mi][ni] = __builtin_amdgcn_mfma_f32_16x16x32_bf16(
                        afr[mi], bfr[ni], acc[mi][ni], 0, 0, 0);
        }
        __syncthreads();
    }

    if constexpr (EPI == 1) {
#pragma unroll
        for (int ni = 0; ni < 4; ++ni) {
            int col = ncol0 + wn * 64 + ni * 16 + lr;
#pragma unroll
            for (int mi = 0; mi < 4; ++mi)
#pragma unroll
                for (int r = 0; r < 4; ++r) {
                    int grow = mrow0 + wm * 64 + mi * 16 + rw + r;
                    Cbf[(size_t)grow * N + col] = f2bf(tanhf(acc[mi][ni][r]));
                }
        }
    } else {
        float bv[4];
#pragma unroll
        for (int ni = 0; ni < 4; ++ni) bv[ni] = bias[ncol0 + wn * 64 + ni * 16 + lr];
#pragma unroll
        for (int mi = 0; mi < 4; ++mi) {
#pragma unroll
            for (int r = 0; r < 4; ++r) {
                int grow = mrow0 + wm * 64 + mi * 16 + rw + r;
                float v[4];
                float mx = -1e30f;
#pragma unroll
                for (int ni = 0; ni < 4; ++ni) {
                    v[ni] = acc[mi][ni][r] + bv[ni];
                    int col = ncol0 + wn * 64 + ni * 16 + lr;
                    Cf[(size_t)grow * N + col] = v[ni];
                    mx = fmaxf(mx, v[ni]);
                }
#pragma unroll
                for (int d = 1; d <= 8; d <<= 1) mx = fmaxf(mx, __shfl_xor(mx, d));
                float ssum = 0.f;
#pragma unroll
                for (int ni = 0; ni < 4; ++ni) ssum += __expf(v[ni] - mx);
#pragma unroll
                for (int d = 1; d <= 8; d <<= 1) ssum += __shfl_xor(ssum, d);
                if (lr == 0) {
                    int lrow = wm * 64 + mi * 16 + rw + r;
                    part_m[wn][lrow] = mx;
                    part_s[wn][lrow] = ssum;
                }
            }
        }
        __syncthreads();
        if (tid < 128) {
            float m0v = part_m[0][tid], m1v = part_m[1][tid];
            float mm = fmaxf(m0v, m1v);
            float ssum = part_s[0][tid] * __expf(m0v - mm) + part_s[1][tid] * __expf(m1v - mm);
            int grow = mrow0 + tid;
            pm[(size_t)grow * gridDim.x + blockIdx.x] = mm;
            ps[(size_t)grow * gridDim.x + blockIdx.x] = ssum;
        }
    }
}

// ---------------- LSTM scan: r5-proven structure, staging conflict/coalesce fix ----
// 256 blocks x 128 threads (2 jj/block). hT[k][b] fp32 exchange via coh_store +
// batched uncached loads. ONLY change vs passing r5: strided chunk assignment in
// the h staging (chunk = i*128+tid) -> coalesced global loads + conflict-free
// ds_write_b128 (was 512B/thread stride: 32-way write conflicts, 5.9e7 counter).
__global__ __launch_bounds__(128)
void k_lstm_scan(const float* __restrict__ xpartT, const float* __restrict__ Whh,
                 const float* __restrict__ hT0, const float* __restrict__ c0,
                 float* __restrict__ hTA, float* __restrict__ hTB,
                 float* __restrict__ Hall, unsigned short* __restrict__ catbuf,
                 float* __restrict__ hf, float* __restrict__ cf,
                 int* __restrict__ cnt) {
    __shared__ float h_lds[DH * 32];     // [k][b]  64 KB
    __shared__ float W_lds[8 * DH];      // [(g*2+jl)][k]  16 KB

    const int tid = threadIdx.x;
    const int b = tid & 31;
    const int kh = (tid >> 5) & 1;       // k-half; partner lane = lane^32 (same wave)
    const int jl = tid >> 6;             // 0..1
    const int jj = blockIdx.x * 2 + jl;
    const int nblk = gridDim.x;

    // stage this block's 8 W_hh rows once
    for (int i = tid; i < 8 * DH / 4; i += 128) {
        int rr = i >> 7;                 // 0..7 = g*2 + jlr
        int c4 = i & 127;
        int g = rr >> 1, jlr = rr & 1;
        float4 v = *(const float4*)(Whh + ((size_t)(g * DH + blockIdx.x * 2 + jlr)) * DH + c4 * 4);
        *(float4*)&W_lds[rr * DH + c4 * 4] = v;
    }

    float creg = c0[b * DH + jj];        // used only by kh==0 lanes

    const float* wp0 = &W_lds[(0 * 2 + jl) * DH + kh * 256];
    const float* wp1 = &W_lds[(1 * 2 + jl) * DH + kh * 256];
    const float* wp2 = &W_lds[(2 * 2 + jl) * DH + kh * 256];
    const float* wp3 = &W_lds[(3 * 2 + jl) * DH + kh * 256];

    for (int t = 0; t < TT; ++t) {
        const float* hTsrc = (t == 0) ? hT0 : ((t & 1) ? hTA : hTB);
        // ---- h all-gather: strided chunks (chunk = q*128 + tid), 16 in flight ----
#pragma unroll
        for (int rnd = 0; rnd < 2; ++rnd) {
            f32x4 v[16];
#pragma unroll
            for (int q = 0; q < 16; ++q)
                asm volatile("global_load_dwordx4 %0, %1, off sc0 sc1"
                             : "=&v"(v[q]) : "v"(hTsrc + ((rnd * 16 + q) * 128 + tid) * 4));
            asm volatile("s_waitcnt vmcnt(0)" ::: "memory");
            __builtin_amdgcn_sched_barrier(0);
#pragma unroll
            for (int q = 0; q < 16; ++q)
                *(f32x4*)&h_lds[((rnd * 16 + q) * 128 + tid) * 4] = v[q];
        }
        __syncthreads();

        float a0 = 0.f, a1 = 0.f, a2 = 0.f, a3 = 0.f;
        const float* hp = &h_lds[kh * 256 * 32 + b];
#pragma unroll 4
        for (int k4 = 0; k4 < 64; ++k4) {
            float4 v0 = *(const float4*)&wp0[k4 * 4];
            float4 v1 = *(const float4*)&wp1[k4 * 4];
            float4 v2 = *(const float4*)&wp2[k4 * 4];
            float4 v3 = *(const float4*)&wp3[k4 * 4];
            float hx = hp[(k4 * 4 + 0) * 32], hy = hp[(k4 * 4 + 1) * 32];
            float hz = hp[(k4 * 4 + 2) * 32], hw = hp[(k4 * 4 + 3) * 32];
            a0 += hx * v0.x + hy * v0.y + hz * v0.z + hw * v0.w;
            a1 += hx * v1.x + hy * v1.y + hz * v1.z + hw * v1.w;
            a2 += hx * v2.x + hy * v2.y + hz * v2.z + hw * v2.w;
            a3 += hx * v3.x + hy * v3.y + hz * v3.z + hw * v3.w;
        }
        a0 += __shfl_xor(a0, 32);
        a1 += __shfl_xor(a1, 32);
        a2 += __shfl_xor(a2, 32);
        a3 += __shfl_xor(a3, 32);

        if (kh == 0) {
            const float* xt = xpartT + (size_t)t * BB + b;   // + col*NROWS below
            float gi = a0 + xt[(size_t)(0 * DH + jj) * NROWS];
            float gf = a1 + xt[(size_t)(1 * DH + jj) * NROWS];
            float gg = a2 + xt[(size_t)(2 * DH + jj) * NROWS];
            float go = a3 + xt[(size_t)(3 * DH + jj) * NROWS];
            float si = 1.f / (1.f + __expf(-gi));
            float sf = 1.f / (1.f + __expf(-gf));
            float tg = tanhf(gg);
            float so = 1.f / (1.f + __expf(-go));
            creg = sf * creg + si * tg;
            float hn = so * tanhf(creg);
            float* wb = (t & 1) ? hTB : hTA;
            coh_store(&wb[jj * 32 + b], hn);          // write-through to coherence point
            int row = t * BB + b;
            Hall[(size_t)row * DH + jj] = hn;          // normal cached stores
            catbuf[(size_t)row * 1024 + jj] = f2bf(hn);
            if (t == TT - 1) {
                hf[b * DH + jj] = hn;
                cf[b * DH + jj] = creg;
            }
        }

        // ---- lightweight device barrier ----
        __syncthreads();   // drains vmcnt before s_barrier -> h stores done
        if (tid == 0) {
            asm volatile("s_waitcnt vmcnt(0)" ::: "memory");
            __hip_atomic_fetch_add(&cnt[t * 16], 1, __ATOMIC_RELAXED,
                                   __HIP_MEMORY_SCOPE_AGENT);
            while (__hip_atomic_load(&cnt[t * 16], __ATOMIC_RELAXED,
                                     __HIP_MEMORY_SCOPE_AGENT) < nblk) {
                __builtin_amdgcn_s_sleep(1);
            }
        }
        __syncthreads();
    }
}

// ---------------- attention: scores -> softmax -> wctx (per (b, 4 t's)) ----------------
__global__ __launch_bounds__(256)
void k_attn(const float* __restrict__ Hall, const float* __restrict__ ctx,
            unsigned short* __restrict__ catbuf) {
    __shared__ float h4[4][DH];
    __shared__ float p_lds[4][SS];
    __shared__ float l_lds[4];

    const int tid = threadIdx.x;
    const int b = blockIdx.x & 31;
    const int tg = blockIdx.x >> 5;

    for (int i = tid; i < 4 * DH / 4; i += 256) {
        int e = i * 4;
        int ti = e >> 9, k = e & 511;
        float4 v = *(const float4*)(Hall + ((size_t)((tg * 4 + ti) * BB + b)) * DH + k);
        h4[ti][k + 0] = v.x; h4[ti][k + 1] = v.y; h4[ti][k + 2] = v.z; h4[ti][k + 3] = v.w;
    }
    __syncthreads();

    {
        int s = tid;
        float acc[4] = {0.f, 0.f, 0.f, 0.f};
        const float4* cp = (const float4*)(ctx + ((size_t)b * SS + s) * DH);
        for (int kc = 0; kc < DH / 4; ++kc) {
            float4 cv = cp[kc];
#pragma unroll
            for (int i = 0; i < 4; ++i) {
                float4 hv = *(const float4*)&h4[i][kc * 4];
                acc[i] += cv.x * hv.x + cv.y * hv.y + cv.z * hv.z + cv.w * hv.w;
            }
        }
#pragma unroll
        for (int i = 0; i < 4; ++i) p_lds[i][s] = acc[i];
    }
    __syncthreads();

    {
        int w = tid >> 6, l = tid & 63;
        float v0 = p_lds[w][l], v1 = p_lds[w][l + 64];
        float v2 = p_lds[w][l + 128], v3 = p_lds[w][l + 192];
        float mx = fmaxf(fmaxf(v0, v1), fmaxf(v2, v3));
        for (int d = 1; d < 64; d <<= 1) mx = fmaxf(mx, __shfl_xor(mx, d));
        float e0 = __expf(v0 - mx), e1 = __expf(v1 - mx);
        float e2 = __expf(v2 - mx), e3 = __expf(v3 - mx);
        float ssum = e0 + e1 + e2 + e3;
        for (int d = 1; d < 64; d <<= 1) ssum += __shfl_xor(ssum, d);
        p_lds[w][l] = e0; p_lds[w][l + 64] = e1;
        p_lds[w][l + 128] = e2; p_lds[w][l + 192] = e3;
        if (l == 0) l_lds[w] = ssum;
    }
    __syncthreads();

    {
        int d0 = tid * 2;
        float accx[4], accy[4];
#pragma unroll
        for (int i = 0; i < 4; ++i) { accx[i] = 0.f; accy[i] = 0.f; }
        const float* cb = ctx + (size_t)b * SS * DH + d0;
        for (int s = 0; s < SS; ++s) {
            float2 cv = *(const float2*)(cb + (size_t)s * DH);
#pragma unroll
            for (int i = 0; i < 4; ++i) {
                float p = p_lds[i][s];
                accx[i] += p * cv.x;
                accy[i] += p * cv.y;
            }
        }
#pragma unroll
        for (int i = 0; i < 4; ++i) {
            float inv = 1.f / l_lds[i];
            int row = (tg * 4 + i) * BB + b;
            unsigned pack = (unsigned)f2bf(accx[i] * inv) | ((unsigned)f2bf(accy[i] * inv) << 16);
            *(unsigned*)&catbuf[(size_t)row * 1024 + DH + d0] = pack;
        }
    }
}

// ---------------- lse combine + subtract ----------------
__global__ void k_lse(const float* __restrict__ pm, const float* __restrict__ ps,
                      float* __restrict__ lse, int nt) {
    int r = blockIdx.x * blockDim.x + threadIdx.x;
    if (r >= NROWS) return;
    const float* pmr = pm + (size_t)r * nt;
    const float* psr = ps + (size_t)r * nt;
    float m = -1e30f;
    for (int i = 0; i < nt; ++i) m = fmaxf(m, pmr[i]);
    float s = 0.f;
    for (int i = 0; i < nt; ++i) s += psr[i] * __expf(pmr[i] - m);
    lse[r] = m + logf(s);
}

__global__ __launch_bounds__(256)
void k_sub(float* __restrict__ logp, const float* __restrict__ lse) {
    int row = blockIdx.x;
    float L = lse[row];
    float4* p = (float4*)(logp + (size_t)row * VV);
    for (int i = threadIdx.x; i < VV / 4; i += 256) {
        float4 v = p[i];
        v.x -= L; v.y -= L; v.z -= L; v.w -= L;
        p[i] = v;
    }
}

// ---------------- host launch ----------------
extern "C" void kernel_launch(void* const* d_in, const int* in_sizes, int n_in,
                              void* d_out, int out_size, void* d_ws, size_t ws_size,
                              hipStream_t stream) {
    const int*   xseq  = (const int*)d_in[0];
    const float* h0    = (const float*)d_in[1];
    const float* c0    = (const float*)d_in[2];
    const float* ctx   = (const float*)d_in[3];
    const float* emb   = (const float*)d_in[4];
    const float* Wih   = (const float*)d_in[5];
    const float* Whh   = (const float*)d_in[6];
    const float* bih   = (const float*)d_in[7];
    const float* bhh   = (const float*)d_in[8];
    const float* Wattn = (const float*)d_in[9];
    const float* Wout  = (const float*)d_in[10];
    const float* bout  = (const float*)d_in[11];
    float* out = (float*)d_out;

    char* wptr = (char*)d_ws;
    auto carve = [&](size_t bytes) {
        char* p = wptr;
        wptr += (bytes + 255) & ~(size_t)255;
        return p;
    };
    float*          xpartT  = (float*)carve((size_t)NROWS * G4 * 4);
    float*          Hall    = (float*)carve((size_t)NROWS * DH * 4);
    unsigned short* catbf   = (unsigned short*)carve((size_t)NROWS * 1024 * 2);
    unsigned short* outsbf  = (unsigned short*)carve((size_t)NROWS * DH * 2);
    float*          ef32    = (float*)carve((size_t)NROWS * DH * 4);
    unsigned short* Wattnbf = (unsigned short*)carve((size_t)DH * 1024 * 2);
    unsigned short* Woutbf  = (unsigned short*)carve((size_t)VV * DH * 2);
    float*          bsum    = (float*)carve((size_t)G4 * 4);
    float*          hT0     = (float*)carve((size_t)BB * DH * 4);
    float*          hTA     = (float*)carve((size_t)BB * DH * 4);
    float*          hTB     = (float*)carve((size_t)BB * DH * 4);
    int*            cnt     = (int*)carve((size_t)TT * 16 * 4);
    float*          pm      = (float*)carve((size_t)NROWS * 250 * 4);
    float*          ps      = (float*)carve((size_t)NROWS * 250 * 4);
    float*          lse     = (float*)carve((size_t)NROWS * 4);

    // prep
    k_bsum<<<8, 256, 0, stream>>>(bih, bhh, bsum);
    k_convert_bf16<<<256, 256, 0, stream>>>(Wattn, Wattnbf, DH * 1024 / 4);
    k_convert_bf16<<<2048, 256, 0, stream>>>(Wout, Woutbf, VV * DH / 4);
    k_gather_embed32<<<NROWS, 128, 0, stream>>>(xseq, emb, ef32);
    k_scan_init<<<64, 256, 0, stream>>>(h0, hT0, cnt);

    // x_part^T = (e @ W_ih^T + b)^T   -- full fp32, transposed write
    k_sgemm_xpart<<<dim3(16, 16), 256, 0, stream>>>(
        ef32, Wih, bsum, xpartT, NROWS, G4, DH);

    // sequential LSTM scan (cooperative for co-residency; custom barrier inside)
    {
        const float* a0 = xpartT; const float* a1 = Whh;
        const float* a2 = hT0;    const float* a3 = c0;
        float* a4 = hTA; float* a5 = hTB; float* a6 = Hall;
        unsigned short* a7 = catbf;
        float* a8 = out + (size_t)NROWS * VV;           // hf
        float* a9 = a8 + BB * DH;                       // cf
        int* a10 = cnt;
        void* args[] = {&a0, &a1, &a2, &a3, &a4, &a5, &a6, &a7, &a8, &a9, &a10};
        hipLaunchCooperativeKernel((const void*)k_lstm_scan, dim3(NBLK_SCAN), dim3(128),
                                   args, 0, stream);
    }

    // attention (parallel over all t,b)
    k_attn<<<512, 256, 0, stream>>>(Hall, ctx, catbf);

    // outs = tanh(cat @ W_attn^T)  -> bf16
    k_mfma_gemm<1><<<dim3(4, 16), 256, 0, stream>>>(
        catbf, Wattnbf, NROWS, DH, 1024, nullptr, nullptr, outsbf, nullptr, nullptr);

    // logits = outs @ W_out^T + b_out -> d_out (fp32) + softmax partials
    k_mfma_gemm<2><<<dim3(250, 16), 256, 0, stream>>>(
        outsbf, Woutbf, NROWS, VV, DH, bout, out, nullptr, pm, ps);

    // lse + in-place logp
    k_lse<<<8, 256, 0, stream>>>(pm, ps, lse, 250);
    k_sub<<<NROWS, 256, 0, stream>>>(out, lse);
}

// Round 11
// 1090.081 us; speedup vs baseline: 2.2229x; 1.3721x over previous
//
#include <hip/hip_runtime.h>
#include <hip/hip_cooperative_groups.h>
#include <cstdint>
#include <cstddef>

namespace cg = cooperative_groups;

#define TT 64
#define BB 32
#define SS 256
#define DH 512
#define VV 32000
#define NROWS 2048   // T*B
#define G4 2048      // 4*DH
#define NBLK_SCAN 256
#define NLEAF 8
#define LEAF_TARGET (NBLK_SCAN / NLEAF)   // 32 arrivals per leaf

typedef __attribute__((ext_vector_type(8))) short short8;
typedef __attribute__((ext_vector_type(4))) float f32x4;

__device__ __forceinline__ unsigned short f2bf(float x) {
    unsigned u = __float_as_uint(x);
    u += 0x7FFFu + ((u >> 16) & 1u);   // RNE
    return (unsigned short)(u >> 16);
}

__device__ __forceinline__ void gload_lds16(const void* g, void* l) {
    __builtin_amdgcn_global_load_lds(
        (const __attribute__((address_space(1))) unsigned int*)g,
        (__attribute__((address_space(3))) unsigned int*)l, 16, 0, 0);
}

// coherent (agent-scope) dword store -- proven cross-XCD exchange primitive
__device__ __forceinline__ void coh_store(float* p, float v) {
    __hip_atomic_store(p, v, __ATOMIC_RELAXED, __HIP_MEMORY_SCOPE_AGENT);
}

// ---------------- prep kernels ----------------
__global__ void k_convert_bf16(const float* __restrict__ src,
                               unsigned short* __restrict__ dst, int n4) {
    int i = blockIdx.x * blockDim.x + threadIdx.x;
    int stride = gridDim.x * blockDim.x;
    for (; i < n4; i += stride) {
        float4 v = ((const float4*)src)[i];
        ushort4 o;
        o.x = f2bf(v.x); o.y = f2bf(v.y); o.z = f2bf(v.z); o.w = f2bf(v.w);
        ((ushort4*)dst)[i] = o;
    }
}

__global__ void k_gather_embed32(const int* __restrict__ xseq,
                                 const float* __restrict__ emb,
                                 float* __restrict__ ef) {
    int r = blockIdx.x;
    int tok = xseq[r];
    const float4* s = (const float4*)(emb + (size_t)tok * DH);
    float4* d = (float4*)(ef + (size_t)r * DH);
    for (int i = threadIdx.x; i < DH / 4; i += blockDim.x) d[i] = s[i];
}

// zero barrier counters (TT*128 ints) + transpose h0 -> hT0[k][b]
__global__ void k_scan_init(const float* __restrict__ h0, float* __restrict__ hT0,
                            int* __restrict__ cnt) {
    int i = blockIdx.x * blockDim.x + threadIdx.x;
    if (i < TT * 128) cnt[i] = 0;
    if (i < BB * DH) {
        int b = i >> 9, k = i & 511;
        hT0[k * 32 + b] = h0[i];
    }
}

// ---------------- fp32 SGEMM: Ct[N,M] = (A[M,K] @ B[N,K]^T + b1 + b2)^T ----------
__global__ __launch_bounds__(256)
void k_sgemm_xpart(const float* __restrict__ A, const float* __restrict__ B,
                   const float* __restrict__ bias1, const float* __restrict__ bias2,
                   float* __restrict__ Ct, int M, int N, int K) {
    __shared__ float As[16][128];
    __shared__ float Bs[16][132];

    const int tid = threadIdx.x;
    const int tx = tid & 15, ty = tid >> 4;
    const int m0 = blockIdx.y * 128, n0 = blockIdx.x * 128;
    const int r = tid >> 1;
    const int c8 = (tid & 1) * 8;

    float acc[8][8] = {};

    for (int kt = 0; kt < K; kt += 16) {
        float4 a0 = *(const float4*)&A[(size_t)(m0 + r) * K + kt + c8];
        float4 a1 = *(const float4*)&A[(size_t)(m0 + r) * K + kt + c8 + 4];
        float4 b0 = *(const float4*)&B[(size_t)(n0 + r) * K + kt + c8];
        float4 b1 = *(const float4*)&B[(size_t)(n0 + r) * K + kt + c8 + 4];
        __syncthreads();
        As[c8 + 0][r] = a0.x; As[c8 + 1][r] = a0.y; As[c8 + 2][r] = a0.z; As[c8 + 3][r] = a0.w;
        As[c8 + 4][r] = a1.x; As[c8 + 5][r] = a1.y; As[c8 + 6][r] = a1.z; As[c8 + 7][r] = a1.w;
        Bs[c8 + 0][r] = b0.x; Bs[c8 + 1][r] = b0.y; Bs[c8 + 2][r] = b0.z; Bs[c8 + 3][r] = b0.w;
        Bs[c8 + 4][r] = b1.x; Bs[c8 + 5][r] = b1.y; Bs[c8 + 6][r] = b1.z; Bs[c8 + 7][r] = b1.w;
        __syncthreads();
#pragma unroll
        for (int kk = 0; kk < 16; ++kk) {
            float4 av0 = *(const float4*)&As[kk][ty * 8];
            float4 av1 = *(const float4*)&As[kk][ty * 8 + 4];
            float4 bv0 = *(const float4*)&Bs[kk][tx * 8];
            float4 bv1 = *(const float4*)&Bs[kk][tx * 8 + 4];
            float av[8] = {av0.x, av0.y, av0.z, av0.w, av1.x, av1.y, av1.z, av1.w};
            float bv[8] = {bv0.x, bv0.y, bv0.z, bv0.w, bv1.x, bv1.y, bv1.z, bv1.w};
#pragma unroll
            for (int i = 0; i < 8; ++i)
#pragma unroll
                for (int j = 0; j < 8; ++j)
                    acc[i][j] += av[i] * bv[j];
        }
    }
#pragma unroll
    for (int i = 0; i < 8; ++i) {
        int grow = m0 + ty * 8 + i;
#pragma unroll
        for (int j = 0; j < 8; ++j) {
            int col = n0 + tx * 8 + j;
            Ct[(size_t)col * M + grow] = acc[i][j] + bias1[col] + bias2[col];
        }
    }
}

// ---------------- MFMA GEMM: C[M,N] = A[M,K] @ B[N,K]^T (+epilogue) ----------------
template <int EPI>
__global__ __launch_bounds__(256)
void k_mfma_gemm(const unsigned short* __restrict__ A,
                 const unsigned short* __restrict__ B,
                 int M, int N, int K,
                 const float* __restrict__ bias,
                 float* __restrict__ Cf,
                 unsigned short* __restrict__ Cbf,
                 float* __restrict__ pm, float* __restrict__ ps) {
    __shared__ unsigned short A_s[128 * 64];
    __shared__ unsigned short B_s[128 * 64];
    __shared__ float part_m[2][128];
    __shared__ float part_s[2][128];

    const int tid = threadIdx.x;
    const int lane = tid & 63;
    const int wid = tid >> 6;
    const int wm = wid >> 1, wn = wid & 1;
    const int mrow0 = blockIdx.y * 128;
    const int ncol0 = blockIdx.x * 128;
    const int lr = lane & 15;
    const int lk = (lane >> 4) * 8;
    const int rw = (lane >> 4) * 4;

    f32x4 acc[4][4] = {};

    for (int kt = 0; kt < K; kt += 64) {
#pragma unroll
        for (int it = 0; it < 4; ++it) {
            int chunk = it * 256 + tid;
            int r = chunk >> 3;
            int c = (chunk & 7) * 8;
            gload_lds16(A + (size_t)(mrow0 + r) * K + kt + c, (void*)(A_s + chunk * 8));
            gload_lds16(B + (size_t)(ncol0 + r) * K + kt + c, (void*)(B_s + chunk * 8));
        }
        __syncthreads();
#pragma unroll
        for (int kk = 0; kk < 2; ++kk) {
            short8 afr[4], bfr[4];
#pragma unroll
            for (int i = 0; i < 4; ++i) {
                afr[i] = *(const short8*)&A_s[(wm * 64 + i * 16 + lr) * 64 + kk * 32 + lk];
                bfr[i] = *(const short8*)&B_s[(wn * 64 + i * 16 + lr) * 64 + kk * 32 + lk];
            }
#pragma unroll
            for (int mi = 0; mi < 4; ++mi)
#pragma unroll
                for (int ni = 0; ni < 4; ++ni)
                    acc[mi][ni] = __builtin_amdgcn_mfma_f32_16x16x32_bf16(
                        afr[mi], bfr[ni], acc[mi][ni], 0, 0, 0);
        }
        __syncthreads();
    }

    if constexpr (EPI == 1) {
#pragma unroll
        for (int ni = 0; ni < 4; ++ni) {
            int col = ncol0 + wn * 64 + ni * 16 + lr;
#pragma unroll
            for (int mi = 0; mi < 4; ++mi)
#pragma unroll
                for (int r = 0; r < 4; ++r) {
                    int grow = mrow0 + wm * 64 + mi * 16 + rw + r;
                    Cbf[(size_t)grow * N + col] = f2bf(tanhf(acc[mi][ni][r]));
                }
        }
    } else {
        float bv[4];
#pragma unroll
        for (int ni = 0; ni < 4; ++ni) bv[ni] = bias[ncol0 + wn * 64 + ni * 16 + lr];
#pragma unroll
        for (int mi = 0; mi < 4; ++mi) {
#pragma unroll
            for (int r = 0; r < 4; ++r) {
                int grow = mrow0 + wm * 64 + mi * 16 + rw + r;
                float v[4];
                float mx = -1e30f;
#pragma unroll
                for (int ni = 0; ni < 4; ++ni) {
                    v[ni] = acc[mi][ni][r] + bv[ni];
                    int col = ncol0 + wn * 64 + ni * 16 + lr;
                    Cf[(size_t)grow * N + col] = v[ni];
                    mx = fmaxf(mx, v[ni]);
                }
#pragma unroll
                for (int d = 1; d <= 8; d <<= 1) mx = fmaxf(mx, __shfl_xor(mx, d));
                float ssum = 0.f;
#pragma unroll
                for (int ni = 0; ni < 4; ++ni) ssum += __expf(v[ni] - mx);
#pragma unroll
                for (int d = 1; d <= 8; d <<= 1) ssum += __shfl_xor(ssum, d);
                if (lr == 0) {
                    int lrow = wm * 64 + mi * 16 + rw + r;
                    part_m[wn][lrow] = mx;
                    part_s[wn][lrow] = ssum;
                }
            }
        }
        __syncthreads();
        if (tid < 128) {
            float m0v = part_m[0][tid], m1v = part_m[1][tid];
            float mm = fmaxf(m0v, m1v);
            float ssum = part_s[0][tid] * __expf(m0v - mm) + part_s[1][tid] * __expf(m1v - mm);
            int grow = mrow0 + tid;
            pm[(size_t)grow * gridDim.x + blockIdx.x] = mm;
            ps[(size_t)grow * gridDim.x + blockIdx.x] = ssum;
        }
    }
}

// ---------------- LSTM scan: r10-proven structure + 8-leaf barrier tree ----------
// 256 blocks x 128 threads (2 jj/block). hT[k][b] fp32 exchange via coh_store +
// batched uncached loads (strided chunks -> coalesced, conflict-free).
// Changes vs r10 (perf only, same math): (1) barrier arrival spread over 8
// 64B-spaced leaf counters (was 256 serialized RMWs on one line); poll via
// lanes 0..7, one leaf each. (2) single 32-deep stage round (one vmcnt drain).
// (3) xpart bias loads hoisted above the stage (latency hidden under drain).
__global__ __launch_bounds__(128)
void k_lstm_scan(const float* __restrict__ xpartT, const float* __restrict__ Whh,
                 const float* __restrict__ hT0, const float* __restrict__ c0,
                 float* __restrict__ hTA, float* __restrict__ hTB,
                 float* __restrict__ Hall, unsigned short* __restrict__ catbuf,
                 float* __restrict__ hf, float* __restrict__ cf,
                 int* __restrict__ cnt) {
    __shared__ float h_lds[DH * 32];     // [k][b]  64 KB
    __shared__ float W_lds[8 * DH];      // [(g*2+jl)][k]  16 KB

    const int tid = threadIdx.x;
    const int b = tid & 31;
    const int kh = (tid >> 5) & 1;       // k-half; partner lane = lane^32 (same wave)
    const int jl = tid >> 6;             // 0..1
    const int jj = blockIdx.x * 2 + jl;

    // stage this block's 8 W_hh rows once
    for (int i = tid; i < 8 * DH / 4; i += 128) {
        int rr = i >> 7;                 // 0..7 = g*2 + jlr
        int c4 = i & 127;
        int g = rr >> 1, jlr = rr & 1;
        float4 v = *(const float4*)(Whh + ((size_t)(g * DH + blockIdx.x * 2 + jlr)) * DH + c4 * 4);
        *(float4*)&W_lds[rr * DH + c4 * 4] = v;
    }

    float creg = c0[b * DH + jj];        // used only by kh==0 lanes

    const float* wp0 = &W_lds[(0 * 2 + jl) * DH + kh * 256];
    const float* wp1 = &W_lds[(1 * 2 + jl) * DH + kh * 256];
    const float* wp2 = &W_lds[(2 * 2 + jl) * DH + kh * 256];
    const float* wp3 = &W_lds[(3 * 2 + jl) * DH + kh * 256];

    for (int t = 0; t < TT; ++t) {
        // ---- xpart bias prefetch (independent of h; completes under the drain) ----
        const float* xt = xpartT + (size_t)t * BB + b;
        float xg0 = xt[(size_t)(0 * DH + jj) * NROWS];
        float xg1 = xt[(size_t)(1 * DH + jj) * NROWS];
        float xg2 = xt[(size_t)(2 * DH + jj) * NROWS];
        float xg3 = xt[(size_t)(3 * DH + jj) * NROWS];

        const float* hTsrc = (t == 0) ? hT0 : ((t & 1) ? hTA : hTB);
        // ---- h all-gather: strided chunks, 32 loads in flight, one drain ----
        {
            f32x4 v[32];
#pragma unroll
            for (int q = 0; q < 32; ++q)
                asm volatile("global_load_dwordx4 %0, %1, off sc0 sc1"
                             : "=&v"(v[q]) : "v"(hTsrc + (q * 128 + tid) * 4));
            asm volatile("s_waitcnt vmcnt(0)" ::: "memory");
            __builtin_amdgcn_sched_barrier(0);
#pragma unroll
            for (int q = 0; q < 32; ++q)
                *(f32x4*)&h_lds[(q * 128 + tid) * 4] = v[q];
        }
        __syncthreads();

        float a0 = 0.f, a1 = 0.f, a2 = 0.f, a3 = 0.f;
        const float* hp = &h_lds[kh * 256 * 32 + b];
#pragma unroll 4
        for (int k4 = 0; k4 < 64; ++k4) {
            float4 v0 = *(const float4*)&wp0[k4 * 4];
            float4 v1 = *(const float4*)&wp1[k4 * 4];
            float4 v2 = *(const float4*)&wp2[k4 * 4];
            float4 v3 = *(const float4*)&wp3[k4 * 4];
            float hx = hp[(k4 * 4 + 0) * 32], hy = hp[(k4 * 4 + 1) * 32];
            float hz = hp[(k4 * 4 + 2) * 32], hw = hp[(k4 * 4 + 3) * 32];
            a0 += hx * v0.x + hy * v0.y + hz * v0.z + hw * v0.w;
            a1 += hx * v1.x + hy * v1.y + hz * v1.z + hw * v1.w;
            a2 += hx * v2.x + hy * v2.y + hz * v2.z + hw * v2.w;
            a3 += hx * v3.x + hy * v3.y + hz * v3.z + hw * v3.w;
        }
        a0 += __shfl_xor(a0, 32);
        a1 += __shfl_xor(a1, 32);
        a2 += __shfl_xor(a2, 32);
        a3 += __shfl_xor(a3, 32);

        if (kh == 0) {
            float gi = a0 + xg0;
            float gf = a1 + xg1;
            float gg = a2 + xg2;
            float go = a3 + xg3;
            float si = 1.f / (1.f + __expf(-gi));
            float sf = 1.f / (1.f + __expf(-gf));
            float tg = tanhf(gg);
            float so = 1.f / (1.f + __expf(-go));
            creg = sf * creg + si * tg;
            float hn = so * tanhf(creg);
            float* wb = (t & 1) ? hTB : hTA;
            coh_store(&wb[jj * 32 + b], hn);          // write-through to coherence point
            int row = t * BB + b;
            Hall[(size_t)row * DH + jj] = hn;          // normal cached stores
            catbuf[(size_t)row * 1024 + jj] = f2bf(hn);
            if (t == TT - 1) {
                hf[b * DH + jj] = hn;
                cf[b * DH + jj] = creg;
            }
        }

        // ---- device barrier: 8-leaf arrival tree, lanes 0..7 poll one leaf each ----
        __syncthreads();   // drains vmcnt before s_barrier -> h stores done
        if (tid == 0) {
            asm volatile("s_waitcnt vmcnt(0)" ::: "memory");
            __hip_atomic_fetch_add(&cnt[t * 128 + (blockIdx.x & (NLEAF - 1)) * 16], 1,
                                   __ATOMIC_RELAXED, __HIP_MEMORY_SCOPE_AGENT);
        }
        if (tid < NLEAF) {
            while (__hip_atomic_load(&cnt[t * 128 + tid * 16], __ATOMIC_RELAXED,
                                     __HIP_MEMORY_SCOPE_AGENT) < LEAF_TARGET) {
                __builtin_amdgcn_s_sleep(1);
            }
        }
        __syncthreads();
    }
}

// ---------------- attention: scores -> softmax -> wctx (per (b, 4 t's)) ----------------
__global__ __launch_bounds__(256)
void k_attn(const float* __restrict__ Hall, const float* __restrict__ ctx,
            unsigned short* __restrict__ catbuf) {
    __shared__ float h4[4][DH];
    __shared__ float p_lds[4][SS];
    __shared__ float l_lds[4];

    const int tid = threadIdx.x;
    const int b = blockIdx.x & 31;
    const int tg = blockIdx.x >> 5;

    for (int i = tid; i < 4 * DH / 4; i += 256) {
        int e = i * 4;
        int ti = e >> 9, k = e & 511;
        float4 v = *(const float4*)(Hall + ((size_t)((tg * 4 + ti) * BB + b)) * DH + k);
        h4[ti][k + 0] = v.x; h4[ti][k + 1] = v.y; h4[ti][k + 2] = v.z; h4[ti][k + 3] = v.w;
    }
    __syncthreads();

    {
        int s = tid;
        float acc[4] = {0.f, 0.f, 0.f, 0.f};
        const float4* cp = (const float4*)(ctx + ((size_t)b * SS + s) * DH);
        for (int kc = 0; kc < DH / 4; ++kc) {
            float4 cv = cp[kc];
#pragma unroll
            for (int i = 0; i < 4; ++i) {
                float4 hv = *(const float4*)&h4[i][kc * 4];
                acc[i] += cv.x * hv.x + cv.y * hv.y + cv.z * hv.z + cv.w * hv.w;
            }
        }
#pragma unroll
        for (int i = 0; i < 4; ++i) p_lds[i][s] = acc[i];
    }
    __syncthreads();

    {
        int w = tid >> 6, l = tid & 63;
        float v0 = p_lds[w][l], v1 = p_lds[w][l + 64];
        float v2 = p_lds[w][l + 128], v3 = p_lds[w][l + 192];
        float mx = fmaxf(fmaxf(v0, v1), fmaxf(v2, v3));
        for (int d = 1; d < 64; d <<= 1) mx = fmaxf(mx, __shfl_xor(mx, d));
        float e0 = __expf(v0 - mx), e1 = __expf(v1 - mx);
        float e2 = __expf(v2 - mx), e3 = __expf(v3 - mx);
        float ssum = e0 + e1 + e2 + e3;
        for (int d = 1; d < 64; d <<= 1) ssum += __shfl_xor(ssum, d);
        p_lds[w][l] = e0; p_lds[w][l + 64] = e1;
        p_lds[w][l + 128] = e2; p_lds[w][l + 192] = e3;
        if (l == 0) l_lds[w] = ssum;
    }
    __syncthreads();

    {
        int d0 = tid * 2;
        float accx[4], accy[4];
#pragma unroll
        for (int i = 0; i < 4; ++i) { accx[i] = 0.f; accy[i] = 0.f; }
        const float* cb = ctx + (size_t)b * SS * DH + d0;
        for (int s = 0; s < SS; ++s) {
            float2 cv = *(const float2*)(cb + (size_t)s * DH);
#pragma unroll
            for (int i = 0; i < 4; ++i) {
                float p = p_lds[i][s];
                accx[i] += p * cv.x;
                accy[i] += p * cv.y;
            }
        }
#pragma unroll
        for (int i = 0; i < 4; ++i) {
            float inv = 1.f / l_lds[i];
            int row = (tg * 4 + i) * BB + b;
            unsigned pack = (unsigned)f2bf(accx[i] * inv) | ((unsigned)f2bf(accy[i] * inv) << 16);
            *(unsigned*)&catbuf[(size_t)row * 1024 + DH + d0] = pack;
        }
    }
}

// ---------------- fused lse + subtract (one block per row) ----------------
__global__ __launch_bounds__(256)
void k_lsesub(float* __restrict__ logp, const float* __restrict__ pm,
              const float* __restrict__ ps, int nt) {
    __shared__ float sL;
    const int row = blockIdx.x;
    const int tid = threadIdx.x;
    if (tid < 64) {
        const float* pmr = pm + (size_t)row * nt;
        const float* psr = ps + (size_t)row * nt;
        float m = -1e30f;
        for (int i = tid; i < nt; i += 64) m = fmaxf(m, pmr[i]);
        for (int d = 1; d < 64; d <<= 1) m = fmaxf(m, __shfl_xor(m, d));
        float s = 0.f;
        for (int i = tid; i < nt; i += 64) s += psr[i] * __expf(pmr[i] - m);
        for (int d = 1; d < 64; d <<= 1) s += __shfl_xor(s, d);
        if (tid == 0) sL = m + logf(s);
    }
    __syncthreads();
    float L = sL;
    float4* p = (float4*)(logp + (size_t)row * VV);
    for (int i = tid; i < VV / 4; i += 256) {
        float4 v = p[i];
        v.x -= L; v.y -= L; v.z -= L; v.w -= L;
        p[i] = v;
    }
}

// ---------------- host launch ----------------
extern "C" void kernel_launch(void* const* d_in, const int* in_sizes, int n_in,
                              void* d_out, int out_size, void* d_ws, size_t ws_size,
                              hipStream_t stream) {
    const int*   xseq  = (const int*)d_in[0];
    const float* h0    = (const float*)d_in[1];
    const float* c0    = (const float*)d_in[2];
    const float* ctx   = (const float*)d_in[3];
    const float* emb   = (const float*)d_in[4];
    const float* Wih   = (const float*)d_in[5];
    const float* Whh   = (const float*)d_in[6];
    const float* bih   = (const float*)d_in[7];
    const float* bhh   = (const float*)d_in[8];
    const float* Wattn = (const float*)d_in[9];
    const float* Wout  = (const float*)d_in[10];
    const float* bout  = (const float*)d_in[11];
    float* out = (float*)d_out;

    char* wptr = (char*)d_ws;
    auto carve = [&](size_t bytes) {
        char* p = wptr;
        wptr += (bytes + 255) & ~(size_t)255;
        return p;
    };
    float*          xpartT  = (float*)carve((size_t)NROWS * G4 * 4);
    float*          Hall    = (float*)carve((size_t)NROWS * DH * 4);
    unsigned short* catbf   = (unsigned short*)carve((size_t)NROWS * 1024 * 2);
    unsigned short* outsbf  = (unsigned short*)carve((size_t)NROWS * DH * 2);
    float*          ef32    = (float*)carve((size_t)NROWS * DH * 4);
    unsigned short* Wattnbf = (unsigned short*)carve((size_t)DH * 1024 * 2);
    unsigned short* Woutbf  = (unsigned short*)carve((size_t)VV * DH * 2);
    float*          hT0     = (float*)carve((size_t)BB * DH * 4);
    float*          hTA     = (float*)carve((size_t)BB * DH * 4);
    float*          hTB     = (float*)carve((size_t)BB * DH * 4);
    int*            cnt     = (int*)carve((size_t)TT * 128 * 4);
    float*          pm      = (float*)carve((size_t)NROWS * 250 * 4);
    float*          ps      = (float*)carve((size_t)NROWS * 250 * 4);

    // prep
    k_convert_bf16<<<256, 256, 0, stream>>>(Wattn, Wattnbf, DH * 1024 / 4);
    k_convert_bf16<<<2048, 256, 0, stream>>>(Wout, Woutbf, VV * DH / 4);
    k_gather_embed32<<<NROWS, 128, 0, stream>>>(xseq, emb, ef32);
    k_scan_init<<<64, 256, 0, stream>>>(h0, hT0, cnt);

    // x_part^T = (e @ W_ih^T + b_ih + b_hh)^T   -- full fp32, transposed write
    k_sgemm_xpart<<<dim3(16, 16), 256, 0, stream>>>(
        ef32, Wih, bih, bhh, xpartT, NROWS, G4, DH);

    // sequential LSTM scan (cooperative for co-residency; leaf-tree barrier inside)
    {
        const float* a0 = xpartT; const float* a1 = Whh;
        const float* a2 = hT0;    const float* a3 = c0;
        float* a4 = hTA; float* a5 = hTB; float* a6 = Hall;
        unsigned short* a7 = catbf;
        float* a8 = out + (size_t)NROWS * VV;           // hf
        float* a9 = a8 + BB * DH;                       // cf
        int* a10 = cnt;
        void* args[] = {&a0, &a1, &a2, &a3, &a4, &a5, &a6, &a7, &a8, &a9, &a10};
        hipLaunchCooperativeKernel((const void*)k_lstm_scan, dim3(NBLK_SCAN), dim3(128),
                                   args, 0, stream);
    }

    // attention (parallel over all t,b)
    k_attn<<<512, 256, 0, stream>>>(Hall, ctx, catbf);

    // outs = tanh(cat @ W_attn^T)  -> bf16
    k_mfma_gemm<1><<<dim3(4, 16), 256, 0, stream>>>(
        catbf, Wattnbf, NROWS, DH, 1024, nullptr, nullptr, outsbf, nullptr, nullptr);

    // logits = outs @ W_out^T + b_out -> d_out (fp32) + softmax partials
    k_mfma_gemm<2><<<dim3(250, 16), 256, 0, stream>>>(
        outsbf, Woutbf, NROWS, VV, DH, bout, out, nullptr, pm, ps);

    // fused lse + in-place logp
    k_lsesub<<<NROWS, 256, 0, stream>>>(out, pm, ps, 250);
}